// Round 3
// baseline (233.916 us; speedup 1.0000x reference)
//
#include <hip/hip_runtime.h>
#include <stdint.h>

// ---------------------------------------------------------------------------
// MultiHeadPointAttention (B=2, N=8192, K=16, H=4, Cin=64, Cout=128, D=32)
//
//   prep_frags : weights -> bf16 MFMA B-fragment layout in ws (Wqkv/Wo split hi/lo)
//   qkv_kernel : q,k,v = x @ [Wq|Wkv] + bias     (split-bf16 MFMA; 3072 waves)
//   fused_attn : one wave per node (block=64): pos MLP, 3 GEMMs, softmax, agg
//   wo_kernel  : out = agg @ Wo + bo             (split-bf16 MFMA; 2048 waves)
//
// MFMA 16x16x32 bf16 layouts (HW-verified per guide):
//   A[m][k]: m = lane&15, k = (lane>>4)*8 + j
//   B[k][n]: n = lane&15, k = (lane>>4)*8 + j
//   D[r][c]: c = lane&15, r = (lane>>4)*4 + reg
//
// bf16 conversion: gfx950 HW v_cvt_pk_bf16_f32 (RNE, packs 2 f32 -> 1 dword).
//
// R2 bug fixed in R3: qkv_kernel k/v dst offsets were cc-256 / cc-384
// (writing 128 floats low, corrupting k and v). Correct: cc-128 / cc-256.
// ---------------------------------------------------------------------------

typedef __attribute__((ext_vector_type(8))) short short8;
typedef __attribute__((ext_vector_type(4))) float f32x4;
typedef __attribute__((ext_vector_type(4))) unsigned int u32x4;

#define NN_TOT 16384   // B*N
#define PES 136        // LDS row stride in bf16 elems (16B-aligned, 272B rows)

__device__ __forceinline__ uint32_t pk_bf16(float a, float b) {
  uint32_t r;
  asm("v_cvt_pk_bf16_f32 %0, %1, %2" : "=v"(r) : "v"(a), "v"(b));
  return r;  // low half = bf16(a), high half = bf16(b)
}
__device__ __forceinline__ float lo_f(uint32_t p) {
  return __builtin_bit_cast(float, p << 16);
}
__device__ __forceinline__ float hi_f(uint32_t p) {
  return __builtin_bit_cast(float, p & 0xffff0000u);
}
__device__ __forceinline__ short f2bf_rne(float f) {   // software fallback (prep only)
  uint32_t u = __builtin_bit_cast(uint32_t, f);
  uint32_t r = (u + 0x7FFFu + ((u >> 16) & 1u)) >> 16;
  return (short)r;
}
__device__ __forceinline__ float bf2f(unsigned short s) {
  uint32_t u = ((uint32_t)s) << 16;
  return __builtin_bit_cast(float, u);
}

// ---------------------------------------------------------------------------
// ws layout (bytes): fqh 0 / fql 49152 / fwp2 98304 / fwa1 131072 /
//   fwa2 163840 / fwoh 196608 / fwol 229376 / q 262144 (+8MB k, +16MB v, +24MB agg)
// ---------------------------------------------------------------------------

__global__ __launch_bounds__(256) void prep_frags(
    const float* __restrict__ Wq, const float* __restrict__ Wkv,
    const float* __restrict__ Wp2, const float* __restrict__ Wa1,
    const float* __restrict__ Wa2, const float* __restrict__ Wo,
    short* __restrict__ fqh, short* __restrict__ fql,
    short* __restrict__ fwp2, short* __restrict__ fwa1, short* __restrict__ fwa2,
    short* __restrict__ fwoh, short* __restrict__ fwol) {
  int r = blockIdx.x * 256 + threadIdx.x;   // grid = 44*256 = 11264 exact
  if (r < 3072) {
    int t = r >> 7, rem = r & 127, s = rem >> 6, lane = rem & 63;
    int quad = lane >> 4, l15 = lane & 15;
    int col = t * 16 + l15;
    #pragma unroll
    for (int j = 0; j < 8; j++) {
      int i = 32 * s + quad * 8 + j;
      float wv = (col < 128) ? Wq[i * 128 + col] : Wkv[i * 256 + (col - 128)];
      short hi = f2bf_rne(wv);
      fqh[r * 8 + j] = hi;
      fql[r * 8 + j] = f2bf_rne(wv - bf2f((unsigned short)hi));
    }
  } else {
    int r2 = r - 3072;
    int mat = r2 >> 11;        // 0:Wp2 1:Wa1 2:Wa2 3:Wo
    int rr = r2 & 2047;
    int t = rr >> 8, rem = rr & 255, s = rem >> 6, lane = rem & 63;
    int quad = lane >> 4, l15 = lane & 15;
    int col = t * 16 + l15;
    const float* W = (mat == 0) ? Wp2 : (mat == 1) ? Wa1 : (mat == 2) ? Wa2 : Wo;
    #pragma unroll
    for (int j = 0; j < 8; j++) {
      int i = 32 * s + quad * 8 + j;
      float wv = W[i * 128 + col];
      short hi = f2bf_rne(wv);
      if (mat == 3) {
        fwoh[rr * 8 + j] = hi;
        fwol[rr * 8 + j] = f2bf_rne(wv - bf2f((unsigned short)hi));
      } else if (mat == 0) fwp2[rr * 8 + j] = hi;
      else if (mat == 1)   fwa1[rr * 8 + j] = hi;
      else                 fwa2[rr * 8 + j] = hi;
    }
  }
}

// Build split hi/lo bf16 A-fragments from 8 consecutive f32.
__device__ __forceinline__ void split_frag(const f32x4 x0, const f32x4 x1,
                                           short8& ah, short8& al) {
  uint32_t h01 = pk_bf16(x0[0], x0[1]);
  uint32_t h23 = pk_bf16(x0[2], x0[3]);
  uint32_t h45 = pk_bf16(x1[0], x1[1]);
  uint32_t h67 = pk_bf16(x1[2], x1[3]);
  u32x4 hh = {h01, h23, h45, h67};
  ah = __builtin_bit_cast(short8, hh);
  uint32_t l01 = pk_bf16(x0[0] - lo_f(h01), x0[1] - hi_f(h01));
  uint32_t l23 = pk_bf16(x0[2] - lo_f(h23), x0[3] - hi_f(h23));
  uint32_t l45 = pk_bf16(x1[0] - lo_f(h45), x1[1] - hi_f(h45));
  uint32_t l67 = pk_bf16(x1[2] - lo_f(h67), x1[3] - hi_f(h67));
  u32x4 ll = {l01, l23, l45, l67};
  al = __builtin_bit_cast(short8, ll);
}

// q,k,v projection. wave = (node-group g, section sec: 0=q 1=k 2=v).
// 3072 waves = 768 blocks.
__global__ __launch_bounds__(256) void qkv_kernel(
    const float* __restrict__ x, const float* __restrict__ bq,
    const float* __restrict__ bkv,
    const short* __restrict__ fqh, const short* __restrict__ fql,
    float* __restrict__ q, float* __restrict__ k, float* __restrict__ v) {
  int wid = blockIdx.x * 4 + (threadIdx.x >> 6);
  int g = wid / 3, sec = wid % 3;
  int lane = threadIdx.x & 63, quad = lane >> 4, l15 = lane & 15;
  int base = g * 16;

  short8 ah[2], al[2];
  #pragma unroll
  for (int s = 0; s < 2; s++) {
    const float* xp = x + (base + l15) * 64 + 32 * s + quad * 8;
    f32x4 x0 = *reinterpret_cast<const f32x4*>(xp);
    f32x4 x1 = *reinterpret_cast<const f32x4*>(xp + 4);
    split_frag(x0, x1, ah[s], al[s]);
  }

  int c = sec * 128 + l15;  // column base for this wave's l15
  float* dst;
  float biasv;
  #pragma unroll
  for (int tt = 0; tt < 8; tt++) {
    int t = sec * 8 + tt;
    f32x4 acc = {0.f, 0.f, 0.f, 0.f};
    #pragma unroll
    for (int s = 0; s < 2; s++) {
      short8 bh = *reinterpret_cast<const short8*>(fqh + ((t * 2 + s) * 64 + lane) * 8);
      short8 bl = *reinterpret_cast<const short8*>(fql + ((t * 2 + s) * 64 + lane) * 8);
      acc = __builtin_amdgcn_mfma_f32_16x16x32_bf16(ah[s], bh, acc, 0, 0, 0);
      acc = __builtin_amdgcn_mfma_f32_16x16x32_bf16(ah[s], bl, acc, 0, 0, 0);
      acc = __builtin_amdgcn_mfma_f32_16x16x32_bf16(al[s], bh, acc, 0, 0, 0);
    }
    int cc = c + tt * 16;     // global column 0..383
    if (sec == 0)      { biasv = bq[cc];        dst = q + cc; }
    else if (sec == 1) { biasv = bkv[cc - 128]; dst = k + (cc - 128); }   // FIXED
    else               { biasv = bkv[cc - 128]; dst = v + (cc - 256); }   // FIXED
    #pragma unroll
    for (int r = 0; r < 4; r++) {
      int node = base + quad * 4 + r;
      dst[node * 128] = acc[r] + biasv;
    }
  }
}

// Fused per-node attention: ONE WAVE PER NODE (block = 64, wave-private LDS).
__global__ __launch_bounds__(64, 4) void fused_attn(
    const float* __restrict__ pos, const int* __restrict__ idx,
    const float* __restrict__ Wp1, const float* __restrict__ bp1,
    const float* __restrict__ bp2, const float* __restrict__ ba1,
    const float* __restrict__ ba2,
    const short* __restrict__ fwp2, const short* __restrict__ fwa1,
    const short* __restrict__ fwa2,
    const float* __restrict__ qg, const float* __restrict__ kg,
    const float* __restrict__ vg, float* __restrict__ agg) {
  __shared__ __align__(16) unsigned short pe_s[16 * PES];   // pos_enc bf16
  __shared__ __align__(16) unsigned short hid_s[16 * PES];  // hidden bf16 (reused)
  __shared__ int sidx[16];
  __shared__ float spd[16][4];
  __shared__ __align__(16) float sq[128];

  const int lane = threadIdx.x;
  const int quad = lane >> 4;
  const int l15 = lane & 15;
  const int nn = blockIdx.x;                // flat node id
  const int b = nn >> 13;

  // ---- stage neighbor idx, pos_diff, q ----
  if (lane < 16) {
    int ji = idx[nn * 16 + lane];
    int jn = b * 8192 + ji;
    sidx[lane] = jn;
    spd[lane][0] = pos[nn * 3 + 0] - pos[jn * 3 + 0];
    spd[lane][1] = pos[nn * 3 + 1] - pos[jn * 3 + 1];
    spd[lane][2] = pos[nn * 3 + 2] - pos[jn * 3 + 2];
  }
  sq[lane]      = qg[nn * 128 + lane];
  sq[lane + 64] = qg[nn * 128 + 64 + lane];
  __syncthreads();

  // ---- prefetch k-gather (latency hides behind MLP + GEMM1) ----
  f32x4 kA[4], kB[4];
  {
    const float* kp = kg + sidx[l15] * 128;
    #pragma unroll
    for (int s = 0; s < 4; s++) {
      kA[s] = *reinterpret_cast<const f32x4*>(kp + 32 * s + quad * 8);
      kB[s] = *reinterpret_cast<const f32x4*>(kp + 32 * s + quad * 8 + 4);
    }
  }

  // ---- pos MLP layer 1 (f32 VALU): relu(pos_diff @ Wp1 + bp1) -> hid_s ----
  {
    const int c0 = lane, c1 = lane + 64;
    float w00 = Wp1[c0], w01 = Wp1[128 + c0], w02 = Wp1[256 + c0], b0 = bp1[c0];
    float w10 = Wp1[c1], w11 = Wp1[128 + c1], w12 = Wp1[256 + c1], b1 = bp1[c1];
    #pragma unroll
    for (int m = 0; m < 16; m++) {
      float d0 = spd[m][0], d1 = spd[m][1], d2 = spd[m][2];
      float h0 = fmaxf(b0 + d0 * w00 + d1 * w01 + d2 * w02, 0.f);
      float h1 = fmaxf(b1 + d0 * w10 + d1 * w11 + d2 * w12, 0.f);
      uint32_t p = pk_bf16(h0, h1);
      hid_s[m * PES + c0] = (unsigned short)p;
      hid_s[m * PES + c1] = (unsigned short)(p >> 16);
    }
  }
  __syncthreads();

  f32x4 acc[8];

  // ---- GEMM1: pos_enc = pos_hidden @ Wp2 + bp2 -> pe_s (bf16) ----
  #pragma unroll
  for (int t = 0; t < 8; t++) acc[t] = (f32x4){0.f, 0.f, 0.f, 0.f};
  #pragma unroll
  for (int s = 0; s < 4; s++) {
    short8 a = *reinterpret_cast<const short8*>(&hid_s[l15 * PES + 32 * s + quad * 8]);
    #pragma unroll
    for (int t = 0; t < 8; t++) {
      short8 bf = *reinterpret_cast<const short8*>(fwp2 + ((t * 4 + s) * 64 + lane) * 8);
      acc[t] = __builtin_amdgcn_mfma_f32_16x16x32_bf16(a, bf, acc[t], 0, 0, 0);
    }
  }
  #pragma unroll
  for (int t = 0; t < 8; t++) {
    int c = 16 * t + l15;
    float bb = bp2[c];
    uint32_t p01 = pk_bf16(acc[t][0] + bb, acc[t][1] + bb);
    uint32_t p23 = pk_bf16(acc[t][2] + bb, acc[t][3] + bb);
    pe_s[(quad * 4 + 0) * PES + c] = (unsigned short)p01;
    pe_s[(quad * 4 + 1) * PES + c] = (unsigned short)(p01 >> 16);
    pe_s[(quad * 4 + 2) * PES + c] = (unsigned short)p23;
    pe_s[(quad * 4 + 3) * PES + c] = (unsigned short)(p23 >> 16);
  }
  __syncthreads();

  // ---- GEMM2: rel = (k_n - q + pos_enc);  hidden = relu(rel @ Wa1 + ba1) ----
  #pragma unroll
  for (int t = 0; t < 8; t++) acc[t] = (f32x4){0.f, 0.f, 0.f, 0.f};
  #pragma unroll
  for (int s = 0; s < 4; s++) {
    int ch0 = 32 * s + quad * 8;
    f32x4 q0 = *reinterpret_cast<const f32x4*>(&sq[ch0]);
    f32x4 q1 = *reinterpret_cast<const f32x4*>(&sq[ch0 + 4]);
    short8 pp = *reinterpret_cast<const short8*>(&pe_s[l15 * PES + ch0]);
    uint32_t a0 = pk_bf16(kA[s][0] - q0[0] + bf2f((unsigned short)pp[0]),
                          kA[s][1] - q0[1] + bf2f((unsigned short)pp[1]));
    uint32_t a1 = pk_bf16(kA[s][2] - q0[2] + bf2f((unsigned short)pp[2]),
                          kA[s][3] - q0[3] + bf2f((unsigned short)pp[3]));
    uint32_t a2 = pk_bf16(kB[s][0] - q1[0] + bf2f((unsigned short)pp[4]),
                          kB[s][1] - q1[1] + bf2f((unsigned short)pp[5]));
    uint32_t a3 = pk_bf16(kB[s][2] - q1[2] + bf2f((unsigned short)pp[6]),
                          kB[s][3] - q1[3] + bf2f((unsigned short)pp[7]));
    u32x4 av = {a0, a1, a2, a3};
    short8 a = __builtin_bit_cast(short8, av);
    #pragma unroll
    for (int t = 0; t < 8; t++) {
      short8 bf = *reinterpret_cast<const short8*>(fwa1 + ((t * 4 + s) * 64 + lane) * 8);
      acc[t] = __builtin_amdgcn_mfma_f32_16x16x32_bf16(a, bf, acc[t], 0, 0, 0);
    }
  }
  #pragma unroll
  for (int t = 0; t < 8; t++) {
    int c = 16 * t + l15;
    float bb = ba1[c];
    uint32_t p01 = pk_bf16(fmaxf(acc[t][0] + bb, 0.f), fmaxf(acc[t][1] + bb, 0.f));
    uint32_t p23 = pk_bf16(fmaxf(acc[t][2] + bb, 0.f), fmaxf(acc[t][3] + bb, 0.f));
    hid_s[(quad * 4 + 0) * PES + c] = (unsigned short)p01;
    hid_s[(quad * 4 + 1) * PES + c] = (unsigned short)(p01 >> 16);
    hid_s[(quad * 4 + 2) * PES + c] = (unsigned short)p23;
    hid_s[(quad * 4 + 3) * PES + c] = (unsigned short)(p23 >> 16);
  }
  __syncthreads();

  // ---- GEMM3: attn = hidden @ Wa2 + ba2 ----
  #pragma unroll
  for (int t = 0; t < 8; t++) acc[t] = (f32x4){0.f, 0.f, 0.f, 0.f};
  #pragma unroll
  for (int s = 0; s < 4; s++) {
    short8 a = *reinterpret_cast<const short8*>(&hid_s[l15 * PES + 32 * s + quad * 8]);
    #pragma unroll
    for (int t = 0; t < 8; t++) {
      short8 bf = *reinterpret_cast<const short8*>(fwa2 + ((t * 4 + s) * 64 + lane) * 8);
      acc[t] = __builtin_amdgcn_mfma_f32_16x16x32_bf16(a, bf, acc[t], 0, 0, 0);
    }
  }

  // ---- softmax over K=16 (per channel) + aggregation ----
  int vb0 = sidx[quad * 4 + 0] * 128;
  int vb1 = sidx[quad * 4 + 1] * 128;
  int vb2 = sidx[quad * 4 + 2] * 128;
  int vb3 = sidx[quad * 4 + 3] * 128;
  #pragma unroll
  for (int t = 0; t < 8; t++) {
    int c = 16 * t + l15;
    float bb = ba2[c];
    float lg0 = acc[t][0] + bb, lg1 = acc[t][1] + bb;
    float lg2 = acc[t][2] + bb, lg3 = acc[t][3] + bb;
    float mx = fmaxf(fmaxf(lg0, lg1), fmaxf(lg2, lg3));
    mx = fmaxf(mx, __shfl_xor(mx, 16));
    mx = fmaxf(mx, __shfl_xor(mx, 32));
    float e0 = __expf(lg0 - mx), e1 = __expf(lg1 - mx);
    float e2 = __expf(lg2 - mx), e3 = __expf(lg3 - mx);
    float ls = e0 + e1 + e2 + e3;
    ls += __shfl_xor(ls, 16);
    ls += __shfl_xor(ls, 32);
    float p = e0 * (vg[vb0 + c] + bf2f(pe_s[(quad * 4 + 0) * PES + c]))
            + e1 * (vg[vb1 + c] + bf2f(pe_s[(quad * 4 + 1) * PES + c]))
            + e2 * (vg[vb2 + c] + bf2f(pe_s[(quad * 4 + 2) * PES + c]))
            + e3 * (vg[vb3 + c] + bf2f(pe_s[(quad * 4 + 3) * PES + c]));
    p += __shfl_xor(p, 16);
    p += __shfl_xor(p, 32);
    if (quad == 0) agg[nn * 128 + c] = p * __builtin_amdgcn_rcpf(ls);
  }
}

// Final projection: out = agg @ Wo + bo. wave = (node-group, t-half). 2048 waves.
__global__ __launch_bounds__(256) void wo_kernel(
    const float* __restrict__ agg, const float* __restrict__ bo,
    const short* __restrict__ fh, const short* __restrict__ fl,
    float* __restrict__ out) {
  int wid = blockIdx.x * 4 + (threadIdx.x >> 6);
  int g = wid >> 1, half = wid & 1;
  int lane = threadIdx.x & 63, quad = lane >> 4, l15 = lane & 15;
  int base = g * 16;

  short8 ah[4], al[4];
  #pragma unroll
  for (int s = 0; s < 4; s++) {
    const float* ap = agg + (base + l15) * 128 + 32 * s + quad * 8;
    f32x4 a0 = *reinterpret_cast<const f32x4*>(ap);
    f32x4 a1 = *reinterpret_cast<const f32x4*>(ap + 4);
    split_frag(a0, a1, ah[s], al[s]);
  }
  #pragma unroll
  for (int tt = 0; tt < 4; tt++) {
    int t = half * 4 + tt;
    f32x4 acc = {0.f, 0.f, 0.f, 0.f};
    #pragma unroll
    for (int s = 0; s < 4; s++) {
      short8 bh = *reinterpret_cast<const short8*>(fh + ((t * 4 + s) * 64 + lane) * 8);
      short8 bl = *reinterpret_cast<const short8*>(fl + ((t * 4 + s) * 64 + lane) * 8);
      acc = __builtin_amdgcn_mfma_f32_16x16x32_bf16(ah[s], bh, acc, 0, 0, 0);
      acc = __builtin_amdgcn_mfma_f32_16x16x32_bf16(ah[s], bl, acc, 0, 0, 0);
      acc = __builtin_amdgcn_mfma_f32_16x16x32_bf16(al[s], bh, acc, 0, 0, 0);
    }
    int c = 16 * t + l15;
    float bb = bo[c];
    #pragma unroll
    for (int r = 0; r < 4; r++)
      out[(base + quad * 4 + r) * 128 + c] = acc[r] + bb;
  }
}

extern "C" void kernel_launch(void* const* d_in, const int* in_sizes, int n_in,
                              void* d_out, int out_size, void* d_ws, size_t ws_size,
                              hipStream_t stream) {
  const float* x   = (const float*)d_in[0];
  const float* pos = (const float*)d_in[1];
  const int*   idx = (const int*)d_in[2];
  const float* Wq  = (const float*)d_in[3];
  const float* bq  = (const float*)d_in[4];
  const float* Wkv = (const float*)d_in[5];
  const float* bkv = (const float*)d_in[6];
  const float* Wp1 = (const float*)d_in[7];
  const float* bp1 = (const float*)d_in[8];
  const float* Wp2 = (const float*)d_in[9];
  const float* bp2 = (const float*)d_in[10];
  const float* Wa1 = (const float*)d_in[11];
  const float* ba1 = (const float*)d_in[12];
  const float* Wa2 = (const float*)d_in[13];
  const float* ba2 = (const float*)d_in[14];
  const float* Wo  = (const float*)d_in[15];
  const float* bo  = (const float*)d_in[16];

  char* ws = (char*)d_ws;
  short* fqh  = (short*)(ws + 0);
  short* fql  = (short*)(ws + 49152);
  short* fwp2 = (short*)(ws + 98304);
  short* fwa1 = (short*)(ws + 131072);
  short* fwa2 = (short*)(ws + 163840);
  short* fwoh = (short*)(ws + 196608);
  short* fwol = (short*)(ws + 229376);
  float* qb = (float*)(ws + 262144);
  float* kb = qb + NN_TOT * 128;
  float* vb = kb + NN_TOT * 128;
  float* ab = vb + NN_TOT * 128;

  prep_frags<<<44, 256, 0, stream>>>(Wq, Wkv, Wp2, Wa1, Wa2, Wo,
                                     fqh, fql, fwp2, fwa1, fwa2, fwoh, fwol);
  qkv_kernel<<<768, 256, 0, stream>>>(x, bq, bkv, fqh, fql, qb, kb, vb);
  fused_attn<<<16384, 64, 0, stream>>>(pos, idx, Wp1, bp1, bp2, ba1, ba2,
                                       fwp2, fwa1, fwa2, qb, kb, vb, ab);
  wo_kernel<<<512, 256, 0, stream>>>(ab, bo, fwoh, fwol, (float*)d_out);
}

// Round 4
// 202.807 us; speedup vs baseline: 1.1534x; 1.1534x over previous
//
#include <hip/hip_runtime.h>
#include <stdint.h>

// ---------------------------------------------------------------------------
// MultiHeadPointAttention (B=2, N=8192, K=16, H=4, Cin=64, Cout=128, D=32)
//
//   prep_frags : weights -> bf16 MFMA B-fragment layout in ws (Wqkv/Wo split hi/lo)
//   qkv_kernel : q,k,v = x @ [Wq|Wkv] + bias   (split-bf16 MFMA; NPW=2)
//   fused_attn : block=256 (4 waves, phase-coupled), 2 nodes PER WAVE:
//                pos MLP, 3 GEMMs (B-frag reused across both nodes), softmax, agg
//   wo_kernel  : out = agg @ Wo + bo           (split-bf16 MFMA; NPW=2)
//
// R1->R3 lesson: 4-wave blocks with barriers keep waves phase-locked so all
// waves stream the same B-fragments through L1 together (L1 reuse). 1-wave
// blocks drifted out of phase and thrashed L1 (129us vs 104us). This round:
// coupling restored + HW cvt + NPW=2 B-fragment register reuse.
//
// MFMA 16x16x32 bf16 layouts (HW-verified per guide):
//   A[m][k]: m = lane&15, k = (lane>>4)*8 + j
//   B[k][n]: n = lane&15, k = (lane>>4)*8 + j
//   D[r][c]: c = lane&15, r = (lane>>4)*4 + reg
// ---------------------------------------------------------------------------

typedef __attribute__((ext_vector_type(8))) short short8;
typedef __attribute__((ext_vector_type(4))) float f32x4;
typedef __attribute__((ext_vector_type(4))) unsigned int u32x4;

#define NN_TOT 16384   // B*N
#define PES 136        // LDS row stride in bf16 elems (16B-aligned, 272B rows)

__device__ __forceinline__ uint32_t pk_bf16(float a, float b) {
  uint32_t r;
  asm("v_cvt_pk_bf16_f32 %0, %1, %2" : "=v"(r) : "v"(a), "v"(b));
  return r;  // low half = bf16(a), high half = bf16(b)
}
__device__ __forceinline__ float lo_f(uint32_t p) {
  return __builtin_bit_cast(float, p << 16);
}
__device__ __forceinline__ float hi_f(uint32_t p) {
  return __builtin_bit_cast(float, p & 0xffff0000u);
}
__device__ __forceinline__ short f2bf_rne(float f) {   // software fallback (prep only)
  uint32_t u = __builtin_bit_cast(uint32_t, f);
  uint32_t r = (u + 0x7FFFu + ((u >> 16) & 1u)) >> 16;
  return (short)r;
}
__device__ __forceinline__ float bf2f(unsigned short s) {
  uint32_t u = ((uint32_t)s) << 16;
  return __builtin_bit_cast(float, u);
}

__global__ __launch_bounds__(256) void prep_frags(
    const float* __restrict__ Wq, const float* __restrict__ Wkv,
    const float* __restrict__ Wp2, const float* __restrict__ Wa1,
    const float* __restrict__ Wa2, const float* __restrict__ Wo,
    short* __restrict__ fqh, short* __restrict__ fql,
    short* __restrict__ fwp2, short* __restrict__ fwa1, short* __restrict__ fwa2,
    short* __restrict__ fwoh, short* __restrict__ fwol) {
  int r = blockIdx.x * 256 + threadIdx.x;   // grid = 44*256 = 11264 exact
  if (r < 3072) {
    int t = r >> 7, rem = r & 127, s = rem >> 6, lane = rem & 63;
    int quad = lane >> 4, l15 = lane & 15;
    int col = t * 16 + l15;
    #pragma unroll
    for (int j = 0; j < 8; j++) {
      int i = 32 * s + quad * 8 + j;
      float wv = (col < 128) ? Wq[i * 128 + col] : Wkv[i * 256 + (col - 128)];
      short hi = f2bf_rne(wv);
      fqh[r * 8 + j] = hi;
      fql[r * 8 + j] = f2bf_rne(wv - bf2f((unsigned short)hi));
    }
  } else {
    int r2 = r - 3072;
    int mat = r2 >> 11;        // 0:Wp2 1:Wa1 2:Wa2 3:Wo
    int rr = r2 & 2047;
    int t = rr >> 8, rem = rr & 255, s = rem >> 6, lane = rem & 63;
    int quad = lane >> 4, l15 = lane & 15;
    int col = t * 16 + l15;
    const float* W = (mat == 0) ? Wp2 : (mat == 1) ? Wa1 : (mat == 2) ? Wa2 : Wo;
    #pragma unroll
    for (int j = 0; j < 8; j++) {
      int i = 32 * s + quad * 8 + j;
      float wv = W[i * 128 + col];
      short hi = f2bf_rne(wv);
      if (mat == 3) {
        fwoh[rr * 8 + j] = hi;
        fwol[rr * 8 + j] = f2bf_rne(wv - bf2f((unsigned short)hi));
      } else if (mat == 0) fwp2[rr * 8 + j] = hi;
      else if (mat == 1)   fwa1[rr * 8 + j] = hi;
      else                 fwa2[rr * 8 + j] = hi;
    }
  }
}

// Build split hi/lo bf16 A-fragments from 8 consecutive f32.
__device__ __forceinline__ void split_frag(const f32x4 x0, const f32x4 x1,
                                           short8& ah, short8& al) {
  uint32_t h01 = pk_bf16(x0[0], x0[1]);
  uint32_t h23 = pk_bf16(x0[2], x0[3]);
  uint32_t h45 = pk_bf16(x1[0], x1[1]);
  uint32_t h67 = pk_bf16(x1[2], x1[3]);
  u32x4 hh = {h01, h23, h45, h67};
  ah = __builtin_bit_cast(short8, hh);
  uint32_t l01 = pk_bf16(x0[0] - lo_f(h01), x0[1] - hi_f(h01));
  uint32_t l23 = pk_bf16(x0[2] - lo_f(h23), x0[3] - hi_f(h23));
  uint32_t l45 = pk_bf16(x1[0] - lo_f(h45), x1[1] - hi_f(h45));
  uint32_t l67 = pk_bf16(x1[2] - lo_f(h67), x1[3] - hi_f(h67));
  u32x4 ll = {l01, l23, l45, l67};
  al = __builtin_bit_cast(short8, ll);
}

// q,k,v projection, NPW=2: wave = (group-pair p, sec 0=q 1=k 2=v).
// 512 pairs x 3 secs = 1536 waves = 384 blocks. B-frags reused across 2 groups.
__global__ __launch_bounds__(256) void qkv_kernel(
    const float* __restrict__ x, const float* __restrict__ bq,
    const float* __restrict__ bkv,
    const short* __restrict__ fqh, const short* __restrict__ fql,
    float* __restrict__ q, float* __restrict__ k, float* __restrict__ v) {
  int wid = blockIdx.x * 4 + (threadIdx.x >> 6);   // 0..1535
  int p = wid / 3, sec = wid % 3;
  int lane = threadIdx.x & 63, quad = lane >> 4, l15 = lane & 15;
  int base0 = p * 32, base1 = base0 + 16;

  short8 ah0[2], al0[2], ah1[2], al1[2];
  #pragma unroll
  for (int s = 0; s < 2; s++) {
    const float* xp0 = x + (base0 + l15) * 64 + 32 * s + quad * 8;
    split_frag(*reinterpret_cast<const f32x4*>(xp0),
               *reinterpret_cast<const f32x4*>(xp0 + 4), ah0[s], al0[s]);
    const float* xp1 = x + (base1 + l15) * 64 + 32 * s + quad * 8;
    split_frag(*reinterpret_cast<const f32x4*>(xp1),
               *reinterpret_cast<const f32x4*>(xp1 + 4), ah1[s], al1[s]);
  }

  #pragma unroll
  for (int tt = 0; tt < 8; tt++) {
    int t = sec * 8 + tt;
    f32x4 acc0 = {0.f, 0.f, 0.f, 0.f};
    f32x4 acc1 = {0.f, 0.f, 0.f, 0.f};
    #pragma unroll
    for (int s = 0; s < 2; s++) {
      short8 bh = *reinterpret_cast<const short8*>(fqh + ((t * 2 + s) * 64 + lane) * 8);
      short8 bl = *reinterpret_cast<const short8*>(fql + ((t * 2 + s) * 64 + lane) * 8);
      acc0 = __builtin_amdgcn_mfma_f32_16x16x32_bf16(ah0[s], bh, acc0, 0, 0, 0);
      acc0 = __builtin_amdgcn_mfma_f32_16x16x32_bf16(ah0[s], bl, acc0, 0, 0, 0);
      acc0 = __builtin_amdgcn_mfma_f32_16x16x32_bf16(al0[s], bh, acc0, 0, 0, 0);
      acc1 = __builtin_amdgcn_mfma_f32_16x16x32_bf16(ah1[s], bh, acc1, 0, 0, 0);
      acc1 = __builtin_amdgcn_mfma_f32_16x16x32_bf16(ah1[s], bl, acc1, 0, 0, 0);
      acc1 = __builtin_amdgcn_mfma_f32_16x16x32_bf16(al1[s], bh, acc1, 0, 0, 0);
    }
    int cc = sec * 128 + tt * 16 + l15;   // global column 0..383
    float biasv;
    float* dst;
    if (sec == 0)      { biasv = bq[cc];        dst = q + cc; }
    else if (sec == 1) { biasv = bkv[cc - 128]; dst = k + (cc - 128); }
    else               { biasv = bkv[cc - 128]; dst = v + (cc - 256); }
    #pragma unroll
    for (int r = 0; r < 4; r++) {
      dst[(base0 + quad * 4 + r) * 128] = acc0[r] + biasv;
      dst[(base1 + quad * 4 + r) * 128] = acc1[r] + biasv;
    }
  }
}

// Fused attention: block=256 (4 phase-coupled waves), each wave = 2 nodes.
__global__ __launch_bounds__(256, 2) void fused_attn(
    const float* __restrict__ pos, const int* __restrict__ idx,
    const float* __restrict__ Wp1, const float* __restrict__ bp1,
    const float* __restrict__ bp2, const float* __restrict__ ba1,
    const float* __restrict__ ba2,
    const short* __restrict__ fwp2, const short* __restrict__ fwa1,
    const short* __restrict__ fwa2,
    const float* __restrict__ qg, const float* __restrict__ kg,
    const float* __restrict__ vg, float* __restrict__ agg) {
  __shared__ __align__(16) unsigned short pe_s[4][2][16 * PES];   // pos_enc bf16
  __shared__ __align__(16) unsigned short hid_s[4][2][16 * PES];  // hidden bf16
  __shared__ int sidx[4][2][16];
  __shared__ float spd[4][2][16][4];
  __shared__ __align__(16) float sq[4][2][128];

  const int w = threadIdx.x >> 6;
  const int lane = threadIdx.x & 63;
  const int quad = lane >> 4;
  const int l15 = lane & 15;
  const int nb = (blockIdx.x * 4 + w) * 2;   // first of 2 nodes for this wave

  // ---- stage neighbor idx, pos_diff, q (both nodes) ----
  if (lane < 32) {
    int nn2 = lane >> 4, m = lane & 15;
    int node = nb + nn2;
    int ji = idx[node * 16 + m];
    int jn = (node >> 13) * 8192 + ji;
    sidx[w][nn2][m] = jn;
    spd[w][nn2][m][0] = pos[node * 3 + 0] - pos[jn * 3 + 0];
    spd[w][nn2][m][1] = pos[node * 3 + 1] - pos[jn * 3 + 1];
    spd[w][nn2][m][2] = pos[node * 3 + 2] - pos[jn * 3 + 2];
  }
  #pragma unroll
  for (int nn2 = 0; nn2 < 2; nn2++) {
    sq[w][nn2][lane]      = qg[(nb + nn2) * 128 + lane];
    sq[w][nn2][lane + 64] = qg[(nb + nn2) * 128 + 64 + lane];
  }
  __syncthreads();

  // ---- pos MLP layer 1 (f32 VALU) -> hid_s, both nodes ----
  {
    const int c0 = lane, c1 = lane + 64;
    float w00 = Wp1[c0], w01 = Wp1[128 + c0], w02 = Wp1[256 + c0], b0 = bp1[c0];
    float w10 = Wp1[c1], w11 = Wp1[128 + c1], w12 = Wp1[256 + c1], b1 = bp1[c1];
    #pragma unroll
    for (int nn2 = 0; nn2 < 2; nn2++) {
      #pragma unroll
      for (int m = 0; m < 16; m++) {
        float d0 = spd[w][nn2][m][0], d1 = spd[w][nn2][m][1], d2 = spd[w][nn2][m][2];
        float h0 = fmaxf(b0 + d0 * w00 + d1 * w01 + d2 * w02, 0.f);
        float h1 = fmaxf(b1 + d0 * w10 + d1 * w11 + d2 * w12, 0.f);
        uint32_t pck = pk_bf16(h0, h1);
        hid_s[w][nn2][m * PES + c0] = (unsigned short)pck;
        hid_s[w][nn2][m * PES + c1] = (unsigned short)(pck >> 16);
      }
    }
  }
  __syncthreads();

  f32x4 acc0[8], acc1[8];

  // ---- GEMM1: pos_enc = pos_hidden @ Wp2 + bp2 -> pe_s ----
  #pragma unroll
  for (int t = 0; t < 8; t++) { acc0[t] = (f32x4){0,0,0,0}; acc1[t] = (f32x4){0,0,0,0}; }
  #pragma unroll
  for (int s = 0; s < 4; s++) {
    short8 a0 = *reinterpret_cast<const short8*>(&hid_s[w][0][l15 * PES + 32 * s + quad * 8]);
    short8 a1 = *reinterpret_cast<const short8*>(&hid_s[w][1][l15 * PES + 32 * s + quad * 8]);
    #pragma unroll
    for (int t = 0; t < 8; t++) {
      short8 bf = *reinterpret_cast<const short8*>(fwp2 + ((t * 4 + s) * 64 + lane) * 8);
      acc0[t] = __builtin_amdgcn_mfma_f32_16x16x32_bf16(a0, bf, acc0[t], 0, 0, 0);
      acc1[t] = __builtin_amdgcn_mfma_f32_16x16x32_bf16(a1, bf, acc1[t], 0, 0, 0);
    }
  }
  #pragma unroll
  for (int t = 0; t < 8; t++) {
    int c = 16 * t + l15;
    float bb = bp2[c];
    uint32_t p01 = pk_bf16(acc0[t][0] + bb, acc0[t][1] + bb);
    uint32_t p23 = pk_bf16(acc0[t][2] + bb, acc0[t][3] + bb);
    pe_s[w][0][(quad * 4 + 0) * PES + c] = (unsigned short)p01;
    pe_s[w][0][(quad * 4 + 1) * PES + c] = (unsigned short)(p01 >> 16);
    pe_s[w][0][(quad * 4 + 2) * PES + c] = (unsigned short)p23;
    pe_s[w][0][(quad * 4 + 3) * PES + c] = (unsigned short)(p23 >> 16);
    uint32_t q01 = pk_bf16(acc1[t][0] + bb, acc1[t][1] + bb);
    uint32_t q23 = pk_bf16(acc1[t][2] + bb, acc1[t][3] + bb);
    pe_s[w][1][(quad * 4 + 0) * PES + c] = (unsigned short)q01;
    pe_s[w][1][(quad * 4 + 1) * PES + c] = (unsigned short)(q01 >> 16);
    pe_s[w][1][(quad * 4 + 2) * PES + c] = (unsigned short)q23;
    pe_s[w][1][(quad * 4 + 3) * PES + c] = (unsigned short)(q23 >> 16);
  }
  __syncthreads();

  // ---- GEMM2: rel = (k_n - q + pos_enc); hidden = relu(rel @ Wa1 + ba1) ----
  #pragma unroll
  for (int t = 0; t < 8; t++) { acc0[t] = (f32x4){0,0,0,0}; acc1[t] = (f32x4){0,0,0,0}; }
  {
    const float* kp0 = kg + sidx[w][0][l15] * 128;
    const float* kp1 = kg + sidx[w][1][l15] * 128;
    #pragma unroll
    for (int s = 0; s < 4; s++) {
      int ch0 = 32 * s + quad * 8;
      f32x4 kA0 = *reinterpret_cast<const f32x4*>(kp0 + ch0);
      f32x4 kB0 = *reinterpret_cast<const f32x4*>(kp0 + ch0 + 4);
      f32x4 kA1 = *reinterpret_cast<const f32x4*>(kp1 + ch0);
      f32x4 kB1 = *reinterpret_cast<const f32x4*>(kp1 + ch0 + 4);
      f32x4 q00 = *reinterpret_cast<const f32x4*>(&sq[w][0][ch0]);
      f32x4 q01 = *reinterpret_cast<const f32x4*>(&sq[w][0][ch0 + 4]);
      f32x4 q10 = *reinterpret_cast<const f32x4*>(&sq[w][1][ch0]);
      f32x4 q11 = *reinterpret_cast<const f32x4*>(&sq[w][1][ch0 + 4]);
      short8 pp0 = *reinterpret_cast<const short8*>(&pe_s[w][0][l15 * PES + ch0]);
      short8 pp1 = *reinterpret_cast<const short8*>(&pe_s[w][1][l15 * PES + ch0]);
      u32x4 av0 = {pk_bf16(kA0[0] - q00[0] + bf2f((unsigned short)pp0[0]),
                           kA0[1] - q00[1] + bf2f((unsigned short)pp0[1])),
                   pk_bf16(kA0[2] - q00[2] + bf2f((unsigned short)pp0[2]),
                           kA0[3] - q00[3] + bf2f((unsigned short)pp0[3])),
                   pk_bf16(kB0[0] - q01[0] + bf2f((unsigned short)pp0[4]),
                           kB0[1] - q01[1] + bf2f((unsigned short)pp0[5])),
                   pk_bf16(kB0[2] - q01[2] + bf2f((unsigned short)pp0[6]),
                           kB0[3] - q01[3] + bf2f((unsigned short)pp0[7]))};
      u32x4 av1 = {pk_bf16(kA1[0] - q10[0] + bf2f((unsigned short)pp1[0]),
                           kA1[1] - q10[1] + bf2f((unsigned short)pp1[1])),
                   pk_bf16(kA1[2] - q10[2] + bf2f((unsigned short)pp1[2]),
                           kA1[3] - q10[3] + bf2f((unsigned short)pp1[3])),
                   pk_bf16(kB1[0] - q11[0] + bf2f((unsigned short)pp1[4]),
                           kB1[1] - q11[1] + bf2f((unsigned short)pp1[5])),
                   pk_bf16(kB1[2] - q11[2] + bf2f((unsigned short)pp1[6]),
                           kB1[3] - q11[3] + bf2f((unsigned short)pp1[7]))};
      short8 a0 = __builtin_bit_cast(short8, av0);
      short8 a1 = __builtin_bit_cast(short8, av1);
      #pragma unroll
      for (int t = 0; t < 8; t++) {
        short8 bf = *reinterpret_cast<const short8*>(fwa1 + ((t * 4 + s) * 64 + lane) * 8);
        acc0[t] = __builtin_amdgcn_mfma_f32_16x16x32_bf16(a0, bf, acc0[t], 0, 0, 0);
        acc1[t] = __builtin_amdgcn_mfma_f32_16x16x32_bf16(a1, bf, acc1[t], 0, 0, 0);
      }
    }
  }
  #pragma unroll
  for (int t = 0; t < 8; t++) {
    int c = 16 * t + l15;
    float bb = ba1[c];
    uint32_t p01 = pk_bf16(fmaxf(acc0[t][0] + bb, 0.f), fmaxf(acc0[t][1] + bb, 0.f));
    uint32_t p23 = pk_bf16(fmaxf(acc0[t][2] + bb, 0.f), fmaxf(acc0[t][3] + bb, 0.f));
    hid_s[w][0][(quad * 4 + 0) * PES + c] = (unsigned short)p01;
    hid_s[w][0][(quad * 4 + 1) * PES + c] = (unsigned short)(p01 >> 16);
    hid_s[w][0][(quad * 4 + 2) * PES + c] = (unsigned short)p23;
    hid_s[w][0][(quad * 4 + 3) * PES + c] = (unsigned short)(p23 >> 16);
    uint32_t q01 = pk_bf16(fmaxf(acc1[t][0] + bb, 0.f), fmaxf(acc1[t][1] + bb, 0.f));
    uint32_t q23 = pk_bf16(fmaxf(acc1[t][2] + bb, 0.f), fmaxf(acc1[t][3] + bb, 0.f));
    hid_s[w][1][(quad * 4 + 0) * PES + c] = (unsigned short)q01;
    hid_s[w][1][(quad * 4 + 1) * PES + c] = (unsigned short)(q01 >> 16);
    hid_s[w][1][(quad * 4 + 2) * PES + c] = (unsigned short)q23;
    hid_s[w][1][(quad * 4 + 3) * PES + c] = (unsigned short)(q23 >> 16);
  }
  __syncthreads();

  // ---- GEMM3: attn = hidden @ Wa2 + ba2 ----
  #pragma unroll
  for (int t = 0; t < 8; t++) { acc0[t] = (f32x4){0,0,0,0}; acc1[t] = (f32x4){0,0,0,0}; }
  #pragma unroll
  for (int s = 0; s < 4; s++) {
    short8 a0 = *reinterpret_cast<const short8*>(&hid_s[w][0][l15 * PES + 32 * s + quad * 8]);
    short8 a1 = *reinterpret_cast<const short8*>(&hid_s[w][1][l15 * PES + 32 * s + quad * 8]);
    #pragma unroll
    for (int t = 0; t < 8; t++) {
      short8 bf = *reinterpret_cast<const short8*>(fwa2 + ((t * 4 + s) * 64 + lane) * 8);
      acc0[t] = __builtin_amdgcn_mfma_f32_16x16x32_bf16(a0, bf, acc0[t], 0, 0, 0);
      acc1[t] = __builtin_amdgcn_mfma_f32_16x16x32_bf16(a1, bf, acc1[t], 0, 0, 0);
    }
  }

  // ---- softmax over K=16 + aggregation, both nodes ----
  int vb0[2][4];
  #pragma unroll
  for (int nn2 = 0; nn2 < 2; nn2++)
    #pragma unroll
    for (int r = 0; r < 4; r++)
      vb0[nn2][r] = sidx[w][nn2][quad * 4 + r] * 128;

  #pragma unroll
  for (int t = 0; t < 8; t++) {
    int c = 16 * t + l15;
    float bb = ba2[c];
    // node 0
    float a_0 = acc0[t][0] + bb, a_1 = acc0[t][1] + bb;
    float a_2 = acc0[t][2] + bb, a_3 = acc0[t][3] + bb;
    float mx0 = fmaxf(fmaxf(a_0, a_1), fmaxf(a_2, a_3));
    mx0 = fmaxf(mx0, __shfl_xor(mx0, 16));
    mx0 = fmaxf(mx0, __shfl_xor(mx0, 32));
    float e00 = __expf(a_0 - mx0), e01 = __expf(a_1 - mx0);
    float e02 = __expf(a_2 - mx0), e03 = __expf(a_3 - mx0);
    float ls0 = e00 + e01 + e02 + e03;
    ls0 += __shfl_xor(ls0, 16);
    ls0 += __shfl_xor(ls0, 32);
    float p0 = e00 * (vg[vb0[0][0] + c] + bf2f(pe_s[w][0][(quad * 4 + 0) * PES + c]))
             + e01 * (vg[vb0[0][1] + c] + bf2f(pe_s[w][0][(quad * 4 + 1) * PES + c]))
             + e02 * (vg[vb0[0][2] + c] + bf2f(pe_s[w][0][(quad * 4 + 2) * PES + c]))
             + e03 * (vg[vb0[0][3] + c] + bf2f(pe_s[w][0][(quad * 4 + 3) * PES + c]));
    p0 += __shfl_xor(p0, 16);
    p0 += __shfl_xor(p0, 32);
    // node 1
    float b_0 = acc1[t][0] + bb, b_1 = acc1[t][1] + bb;
    float b_2 = acc1[t][2] + bb, b_3 = acc1[t][3] + bb;
    float mx1 = fmaxf(fmaxf(b_0, b_1), fmaxf(b_2, b_3));
    mx1 = fmaxf(mx1, __shfl_xor(mx1, 16));
    mx1 = fmaxf(mx1, __shfl_xor(mx1, 32));
    float e10 = __expf(b_0 - mx1), e11 = __expf(b_1 - mx1);
    float e12 = __expf(b_2 - mx1), e13 = __expf(b_3 - mx1);
    float ls1 = e10 + e11 + e12 + e13;
    ls1 += __shfl_xor(ls1, 16);
    ls1 += __shfl_xor(ls1, 32);
    float p1 = e10 * (vg[vb0[1][0] + c] + bf2f(pe_s[w][1][(quad * 4 + 0) * PES + c]))
             + e11 * (vg[vb0[1][1] + c] + bf2f(pe_s[w][1][(quad * 4 + 1) * PES + c]))
             + e12 * (vg[vb0[1][2] + c] + bf2f(pe_s[w][1][(quad * 4 + 2) * PES + c]))
             + e13 * (vg[vb0[1][3] + c] + bf2f(pe_s[w][1][(quad * 4 + 3) * PES + c]));
    p1 += __shfl_xor(p1, 16);
    p1 += __shfl_xor(p1, 32);
    if (quad == 0) {
      agg[nb * 128 + c]       = p0 * __builtin_amdgcn_rcpf(ls0);
      agg[(nb + 1) * 128 + c] = p1 * __builtin_amdgcn_rcpf(ls1);
    }
  }
}

// Final projection, NPW=2: wave = (group-pair, t-half). 1024 waves = 256 blocks.
__global__ __launch_bounds__(256) void wo_kernel(
    const float* __restrict__ agg, const float* __restrict__ bo,
    const short* __restrict__ fh, const short* __restrict__ fl,
    float* __restrict__ out) {
  int wid = blockIdx.x * 4 + (threadIdx.x >> 6);   // 0..1023
  int pr = wid >> 1, half = wid & 1;
  int lane = threadIdx.x & 63, quad = lane >> 4, l15 = lane & 15;
  int base0 = pr * 32, base1 = base0 + 16;

  short8 ah0[4], al0[4], ah1[4], al1[4];
  #pragma unroll
  for (int s = 0; s < 4; s++) {
    const float* a0p = agg + (base0 + l15) * 128 + 32 * s + quad * 8;
    split_frag(*reinterpret_cast<const f32x4*>(a0p),
               *reinterpret_cast<const f32x4*>(a0p + 4), ah0[s], al0[s]);
    const float* a1p = agg + (base1 + l15) * 128 + 32 * s + quad * 8;
    split_frag(*reinterpret_cast<const f32x4*>(a1p),
               *reinterpret_cast<const f32x4*>(a1p + 4), ah1[s], al1[s]);
  }
  #pragma unroll
  for (int tt = 0; tt < 4; tt++) {
    int t = half * 4 + tt;
    f32x4 acc0 = {0.f, 0.f, 0.f, 0.f};
    f32x4 acc1 = {0.f, 0.f, 0.f, 0.f};
    #pragma unroll
    for (int s = 0; s < 4; s++) {
      short8 bh = *reinterpret_cast<const short8*>(fh + ((t * 4 + s) * 64 + lane) * 8);
      short8 bl = *reinterpret_cast<const short8*>(fl + ((t * 4 + s) * 64 + lane) * 8);
      acc0 = __builtin_amdgcn_mfma_f32_16x16x32_bf16(ah0[s], bh, acc0, 0, 0, 0);
      acc0 = __builtin_amdgcn_mfma_f32_16x16x32_bf16(ah0[s], bl, acc0, 0, 0, 0);
      acc0 = __builtin_amdgcn_mfma_f32_16x16x32_bf16(al0[s], bh, acc0, 0, 0, 0);
      acc1 = __builtin_amdgcn_mfma_f32_16x16x32_bf16(ah1[s], bh, acc1, 0, 0, 0);
      acc1 = __builtin_amdgcn_mfma_f32_16x16x32_bf16(ah1[s], bl, acc1, 0, 0, 0);
      acc1 = __builtin_amdgcn_mfma_f32_16x16x32_bf16(al1[s], bh, acc1, 0, 0, 0);
    }
    int c = 16 * t + l15;
    float bb = bo[c];
    #pragma unroll
    for (int r = 0; r < 4; r++) {
      out[(base0 + quad * 4 + r) * 128 + c] = acc0[r] + bb;
      out[(base1 + quad * 4 + r) * 128 + c] = acc1[r] + bb;
    }
  }
}

extern "C" void kernel_launch(void* const* d_in, const int* in_sizes, int n_in,
                              void* d_out, int out_size, void* d_ws, size_t ws_size,
                              hipStream_t stream) {
  const float* x   = (const float*)d_in[0];
  const float* pos = (const float*)d_in[1];
  const int*   idx = (const int*)d_in[2];
  const float* Wq  = (const float*)d_in[3];
  const float* bq  = (const float*)d_in[4];
  const float* Wkv = (const float*)d_in[5];
  const float* bkv = (const float*)d_in[6];
  const float* Wp1 = (const float*)d_in[7];
  const float* bp1 = (const float*)d_in[8];
  const float* Wp2 = (const float*)d_in[9];
  const float* bp2 = (const float*)d_in[10];
  const float* Wa1 = (const float*)d_in[11];
  const float* ba1 = (const float*)d_in[12];
  const float* Wa2 = (const float*)d_in[13];
  const float* ba2 = (const float*)d_in[14];
  const float* Wo  = (const float*)d_in[15];
  const float* bo  = (const float*)d_in[16];

  char* ws = (char*)d_ws;
  short* fqh  = (short*)(ws + 0);
  short* fql  = (short*)(ws + 49152);
  short* fwp2 = (short*)(ws + 98304);
  short* fwa1 = (short*)(ws + 131072);
  short* fwa2 = (short*)(ws + 163840);
  short* fwoh = (short*)(ws + 196608);
  short* fwol = (short*)(ws + 229376);
  float* qb = (float*)(ws + 262144);
  float* kb = qb + NN_TOT * 128;
  float* vb = kb + NN_TOT * 128;
  float* ab = vb + NN_TOT * 128;

  prep_frags<<<44, 256, 0, stream>>>(Wq, Wkv, Wp2, Wa1, Wa2, Wo,
                                     fqh, fql, fwp2, fwa1, fwa2, fwoh, fwol);
  qkv_kernel<<<384, 256, 0, stream>>>(x, bq, bkv, fqh, fql, qb, kb, vb);
  fused_attn<<<2048, 256, 0, stream>>>(pos, idx, Wp1, bp1, bp2, ba1, ba2,
                                       fwp2, fwa1, fwa2, qb, kb, vb, ab);
  wo_kernel<<<256, 256, 0, stream>>>(ab, bo, fwoh, fwol, (float*)d_out);
}

// Round 5
// 194.296 us; speedup vs baseline: 1.2039x; 1.0438x over previous
//
#include <hip/hip_runtime.h>
#include <stdint.h>

// ---------------------------------------------------------------------------
// MultiHeadPointAttention (B=2, N=8192, K=16, H=4, Cin=64, Cout=128, D=32)
//
//   prep_frags    : weights -> bf16 MFMA B-fragment layout in ws
//   qkv_kernel    : q,k,v = x @ [Wq|Wkv] + bias (split-bf16 MFMA; 6144 waves)
//   fused_attn_wo : block=512 (8 waves, 16 nodes, 2/wave).
//                   All 3 GEMM B-matrices staged in LDS (96 KB) once per block;
//                   wave-private transpose stages (no barriers; LDS ops are
//                   in-order within a wave); pe kept in registers (C/D layout
//                   matches aggregation); Wo GEMM fused via sagg LDS stage.
//                   Only 2 __syncthreads per block.
//
// R4 lesson: global-B designs are ~68% latency-stalled regardless of NPW
// (busy ≈ 32%); LDS-B converts the inner loops to ds_read_b128 streams.
//
// MFMA 16x16x32 bf16 layouts (HW-verified):
//   A[m][k]: m = lane&15, k = (lane>>4)*8 + j
//   B[k][n]: n = lane&15, k = (lane>>4)*8 + j
//   D[r][c]: c = lane&15, r = (lane>>4)*4 + reg
// ---------------------------------------------------------------------------

typedef __attribute__((ext_vector_type(8))) short short8;
typedef __attribute__((ext_vector_type(4))) float f32x4;
typedef __attribute__((ext_vector_type(4))) unsigned int u32x4;

#define NN_TOT 16384   // B*N
#define PES 136        // stage row stride in bf16 elems (16B-aligned)

__device__ __forceinline__ uint32_t pk_bf16(float a, float b) {
  uint32_t r;
  asm("v_cvt_pk_bf16_f32 %0, %1, %2" : "=v"(r) : "v"(a), "v"(b));
  return r;  // low = bf16(a), high = bf16(b)
}
__device__ __forceinline__ float lo_f(uint32_t p) {
  return __builtin_bit_cast(float, p << 16);
}
__device__ __forceinline__ float hi_f(uint32_t p) {
  return __builtin_bit_cast(float, p & 0xffff0000u);
}
__device__ __forceinline__ short f2bf_rne(float f) {   // prep only
  uint32_t u = __builtin_bit_cast(uint32_t, f);
  uint32_t r = (u + 0x7FFFu + ((u >> 16) & 1u)) >> 16;
  return (short)r;
}
__device__ __forceinline__ float bf2f(unsigned short s) {
  uint32_t u = ((uint32_t)s) << 16;
  return __builtin_bit_cast(float, u);
}

__global__ __launch_bounds__(256) void prep_frags(
    const float* __restrict__ Wq, const float* __restrict__ Wkv,
    const float* __restrict__ Wp2, const float* __restrict__ Wa1,
    const float* __restrict__ Wa2, const float* __restrict__ Wo,
    short* __restrict__ fqh, short* __restrict__ fql,
    short* __restrict__ fwp2, short* __restrict__ fwa1, short* __restrict__ fwa2,
    short* __restrict__ fwoh, short* __restrict__ fwol) {
  int r = blockIdx.x * 256 + threadIdx.x;   // grid = 44*256 = 11264 exact
  if (r < 3072) {
    int t = r >> 7, rem = r & 127, s = rem >> 6, lane = rem & 63;
    int quad = lane >> 4, l15 = lane & 15;
    int col = t * 16 + l15;
    #pragma unroll
    for (int j = 0; j < 8; j++) {
      int i = 32 * s + quad * 8 + j;
      float wv = (col < 128) ? Wq[i * 128 + col] : Wkv[i * 256 + (col - 128)];
      short hi = f2bf_rne(wv);
      fqh[r * 8 + j] = hi;
      fql[r * 8 + j] = f2bf_rne(wv - bf2f((unsigned short)hi));
    }
  } else {
    int r2 = r - 3072;
    int mat = r2 >> 11;        // 0:Wp2 1:Wa1 2:Wa2 3:Wo
    int rr = r2 & 2047;
    int t = rr >> 8, rem = rr & 255, s = rem >> 6, lane = rem & 63;
    int quad = lane >> 4, l15 = lane & 15;
    int col = t * 16 + l15;
    const float* W = (mat == 0) ? Wp2 : (mat == 1) ? Wa1 : (mat == 2) ? Wa2 : Wo;
    #pragma unroll
    for (int j = 0; j < 8; j++) {
      int i = 32 * s + quad * 8 + j;
      float wv = W[i * 128 + col];
      short hi = f2bf_rne(wv);
      if (mat == 3) {
        fwoh[rr * 8 + j] = hi;
        fwol[rr * 8 + j] = f2bf_rne(wv - bf2f((unsigned short)hi));
      } else if (mat == 0) fwp2[rr * 8 + j] = hi;
      else if (mat == 1)   fwa1[rr * 8 + j] = hi;
      else                 fwa2[rr * 8 + j] = hi;
    }
  }
}

__device__ __forceinline__ void split_frag(const f32x4 x0, const f32x4 x1,
                                           short8& ah, short8& al) {
  uint32_t h01 = pk_bf16(x0[0], x0[1]);
  uint32_t h23 = pk_bf16(x0[2], x0[3]);
  uint32_t h45 = pk_bf16(x1[0], x1[1]);
  uint32_t h67 = pk_bf16(x1[2], x1[3]);
  u32x4 hh = {h01, h23, h45, h67};
  ah = __builtin_bit_cast(short8, hh);
  uint32_t l01 = pk_bf16(x0[0] - lo_f(h01), x0[1] - hi_f(h01));
  uint32_t l23 = pk_bf16(x0[2] - lo_f(h23), x0[3] - hi_f(h23));
  uint32_t l45 = pk_bf16(x1[0] - lo_f(h45), x1[1] - hi_f(h45));
  uint32_t l67 = pk_bf16(x1[2] - lo_f(h67), x1[3] - hi_f(h67));
  u32x4 ll = {l01, l23, l45, l67};
  al = __builtin_bit_cast(short8, ll);
}

// q,k,v projection. wave = (group g, sec 0..2, half 0..1). 6144 waves.
__global__ __launch_bounds__(256) void qkv_kernel(
    const float* __restrict__ x, const float* __restrict__ bq,
    const float* __restrict__ bkv,
    const short* __restrict__ fqh, const short* __restrict__ fql,
    float* __restrict__ q, float* __restrict__ k, float* __restrict__ v) {
  int wid = blockIdx.x * 4 + (threadIdx.x >> 6);   // 0..6143
  int g = wid / 6, r6 = wid % 6, sec = r6 >> 1, hf = r6 & 1;
  int lane = threadIdx.x & 63, quad = lane >> 4, l15 = lane & 15;
  int base = g * 16;

  short8 ah[2], al[2];
  #pragma unroll
  for (int s = 0; s < 2; s++) {
    const float* xp = x + (base + l15) * 64 + 32 * s + quad * 8;
    split_frag(*reinterpret_cast<const f32x4*>(xp),
               *reinterpret_cast<const f32x4*>(xp + 4), ah[s], al[s]);
  }

  #pragma unroll
  for (int tt = 0; tt < 4; tt++) {
    int t = sec * 8 + hf * 4 + tt;
    f32x4 acc = {0.f, 0.f, 0.f, 0.f};
    #pragma unroll
    for (int s = 0; s < 2; s++) {
      short8 bh = *reinterpret_cast<const short8*>(fqh + ((t * 2 + s) * 64 + lane) * 8);
      short8 bl = *reinterpret_cast<const short8*>(fql + ((t * 2 + s) * 64 + lane) * 8);
      acc = __builtin_amdgcn_mfma_f32_16x16x32_bf16(ah[s], bh, acc, 0, 0, 0);
      acc = __builtin_amdgcn_mfma_f32_16x16x32_bf16(ah[s], bl, acc, 0, 0, 0);
      acc = __builtin_amdgcn_mfma_f32_16x16x32_bf16(al[s], bh, acc, 0, 0, 0);
    }
    int cc = t * 16 + l15;      // global column 0..383
    float biasv;
    float* dst;
    if (cc < 128)      { biasv = bq[cc];        dst = q + cc; }
    else if (cc < 256) { biasv = bkv[cc - 128]; dst = k + (cc - 128); }
    else               { biasv = bkv[cc - 128]; dst = v + (cc - 256); }
    #pragma unroll
    for (int r = 0; r < 4; r++)
      dst[(base + quad * 4 + r) * 128] = acc[r] + biasv;
  }
}

// ---------------------------------------------------------------------------
// Fused attention + Wo. Block = 512 threads (8 waves), 16 nodes (2 per wave).
// ---------------------------------------------------------------------------
__global__ __launch_bounds__(512, 2) void fused_attn_wo(
    const float* __restrict__ pos, const int* __restrict__ idx,
    const float* __restrict__ Wp1, const float* __restrict__ bp1,
    const float* __restrict__ bp2, const float* __restrict__ ba1,
    const float* __restrict__ ba2,
    const short* __restrict__ fw_all,   // fwp2|fwa1|fwa2 contiguous (49152 shorts)
    const short* __restrict__ fwoh, const short* __restrict__ fwol,
    const float* __restrict__ bo,
    const float* __restrict__ qg, const float* __restrict__ kg,
    const float* __restrict__ vg, float* __restrict__ out) {
  __shared__ __align__(16) short sB[49152];               // 96 KB: 3 B-matrices
  __shared__ __align__(16) unsigned short stg[8][16 * PES]; // wave-private stage
  __shared__ __align__(16) float sagg[16][132];           // agg for wo phase
  __shared__ float spd[8][2][16][3];
  __shared__ int sidx[8][2][16];

  const int tid = threadIdx.x;
  const int w = tid >> 6;
  const int lane = tid & 63;
  const int quad = lane >> 4, l15 = lane & 15;
  const int nb0 = blockIdx.x * 16;
  const int nbw = nb0 + w * 2;

  // ---- stage neighbor idx + pos_diff (wave-private) ----
  if (lane < 32) {
    int nn2 = lane >> 4, m = lane & 15;
    int node = nbw + nn2;
    int ji = idx[node * 16 + m];
    int jn = ((node >> 13) << 13) + ji;
    sidx[w][nn2][m] = jn;
    spd[w][nn2][m][0] = pos[node * 3 + 0] - pos[jn * 3 + 0];
    spd[w][nn2][m][1] = pos[node * 3 + 1] - pos[jn * 3 + 1];
    spd[w][nn2][m][2] = pos[node * 3 + 2] - pos[jn * 3 + 2];
  }

  // ---- stage all three B-matrices to LDS (96 KB) ----
  {
    const u32x4* src = reinterpret_cast<const u32x4*>(fw_all);
    u32x4* dst = reinterpret_cast<u32x4*>(sB);
    #pragma unroll
    for (int i = 0; i < 12; i++) dst[tid + i * 512] = src[tid + i * 512];
  }
  __syncthreads();   // barrier 1: sB visible (also orders sidx/spd, same wave)

  // ---- prefetch kq = k_n - q (f32, latency hides behind MLP + GEMM1) ----
  f32x4 kq0[2][4], kq1[2][4];
  #pragma unroll
  for (int nn2 = 0; nn2 < 2; nn2++) {
    const float* kp = kg + sidx[w][nn2][l15] * 128;
    const float* qp = qg + (nbw + nn2) * 128;
    #pragma unroll
    for (int s = 0; s < 4; s++) {
      int ch = 32 * s + quad * 8;
      f32x4 ka = *reinterpret_cast<const f32x4*>(kp + ch);
      f32x4 kb = *reinterpret_cast<const f32x4*>(kp + ch + 4);
      f32x4 qa = *reinterpret_cast<const f32x4*>(qp + ch);
      f32x4 qb = *reinterpret_cast<const f32x4*>(qp + ch + 4);
      kq0[nn2][s] = ka - qa;
      kq1[nn2][s] = kb - qb;
    }
  }

  // ---- pos MLP layer 1 -> stage -> A-frags (per node, wave-private) ----
  short8 aP[2][4];
  {
    const int c0 = lane, c1 = lane + 64;
    float wp00 = Wp1[c0], wp01 = Wp1[128 + c0], wp02 = Wp1[256 + c0], bb0 = bp1[c0];
    float wp10 = Wp1[c1], wp11 = Wp1[128 + c1], wp12 = Wp1[256 + c1], bb1 = bp1[c1];
    #pragma unroll
    for (int nn2 = 0; nn2 < 2; nn2++) {
      #pragma unroll
      for (int m = 0; m < 16; m++) {
        float d0 = spd[w][nn2][m][0], d1 = spd[w][nn2][m][1], d2 = spd[w][nn2][m][2];
        float h0 = fmaxf(bb0 + d0 * wp00 + d1 * wp01 + d2 * wp02, 0.f);
        float h1 = fmaxf(bb1 + d0 * wp10 + d1 * wp11 + d2 * wp12, 0.f);
        uint32_t pck = pk_bf16(h0, h1);
        stg[w][m * PES + c0] = (unsigned short)pck;
        stg[w][m * PES + c1] = (unsigned short)(pck >> 16);
      }
      #pragma unroll
      for (int s = 0; s < 4; s++)
        aP[nn2][s] = *reinterpret_cast<const short8*>(&stg[w][l15 * PES + 32 * s + quad * 8]);
    }
  }

  f32x4 acc0[8], acc1[8];

  // ---- GEMM1: pos_enc = pos_hidden @ Wp2 (B from LDS) ----
  #pragma unroll
  for (int t = 0; t < 8; t++) { acc0[t] = (f32x4){0,0,0,0}; acc1[t] = (f32x4){0,0,0,0}; }
  #pragma unroll
  for (int s = 0; s < 4; s++) {
    #pragma unroll
    for (int t = 0; t < 8; t++) {
      short8 bf = *reinterpret_cast<const short8*>(sB + ((t * 4 + s) * 64 + lane) * 8);
      acc0[t] = __builtin_amdgcn_mfma_f32_16x16x32_bf16(aP[0][s], bf, acc0[t], 0, 0, 0);
      acc1[t] = __builtin_amdgcn_mfma_f32_16x16x32_bf16(aP[1][s], bf, acc1[t], 0, 0, 0);
    }
  }

  // ---- pe = acc + bp2: stage -> A layout; keep packed pe in regs ----
  uint32_t pe_pk[2][8][2];
  short8 aR[2][4];
  #pragma unroll
  for (int nn2 = 0; nn2 < 2; nn2++) {
    f32x4* ac = nn2 ? acc1 : acc0;
    #pragma unroll
    for (int t = 0; t < 8; t++) {
      int c = 16 * t + l15;
      float bb = bp2[c];
      uint32_t p01 = pk_bf16(ac[t][0] + bb, ac[t][1] + bb);
      uint32_t p23 = pk_bf16(ac[t][2] + bb, ac[t][3] + bb);
      pe_pk[nn2][t][0] = p01;
      pe_pk[nn2][t][1] = p23;
      stg[w][(quad * 4 + 0) * PES + c] = (unsigned short)p01;
      stg[w][(quad * 4 + 1) * PES + c] = (unsigned short)(p01 >> 16);
      stg[w][(quad * 4 + 2) * PES + c] = (unsigned short)p23;
      stg[w][(quad * 4 + 3) * PES + c] = (unsigned short)(p23 >> 16);
    }
    #pragma unroll
    for (int s = 0; s < 4; s++)
      aR[nn2][s] = *reinterpret_cast<const short8*>(&stg[w][l15 * PES + 32 * s + quad * 8]);
  }

  // ---- GEMM2 A = bf16(kq + pe) ----
  short8 a2[2][4];
  #pragma unroll
  for (int nn2 = 0; nn2 < 2; nn2++) {
    #pragma unroll
    for (int s = 0; s < 4; s++) {
      short8 pp = aR[nn2][s];
      u32x4 av = {pk_bf16(kq0[nn2][s][0] + bf2f((unsigned short)pp[0]),
                          kq0[nn2][s][1] + bf2f((unsigned short)pp[1])),
                  pk_bf16(kq0[nn2][s][2] + bf2f((unsigned short)pp[2]),
                          kq0[nn2][s][3] + bf2f((unsigned short)pp[3])),
                  pk_bf16(kq1[nn2][s][0] + bf2f((unsigned short)pp[4]),
                          kq1[nn2][s][1] + bf2f((unsigned short)pp[5])),
                  pk_bf16(kq1[nn2][s][2] + bf2f((unsigned short)pp[6]),
                          kq1[nn2][s][3] + bf2f((unsigned short)pp[7]))};
      a2[nn2][s] = __builtin_bit_cast(short8, av);
    }
  }

  // ---- GEMM2: hidden = relu(rel @ Wa1 + ba1) ----
  #pragma unroll
  for (int t = 0; t < 8; t++) { acc0[t] = (f32x4){0,0,0,0}; acc1[t] = (f32x4){0,0,0,0}; }
  #pragma unroll
  for (int s = 0; s < 4; s++) {
    #pragma unroll
    for (int t = 0; t < 8; t++) {
      short8 bf = *reinterpret_cast<const short8*>(sB + 16384 + ((t * 4 + s) * 64 + lane) * 8);
      acc0[t] = __builtin_amdgcn_mfma_f32_16x16x32_bf16(a2[0][s], bf, acc0[t], 0, 0, 0);
      acc1[t] = __builtin_amdgcn_mfma_f32_16x16x32_bf16(a2[1][s], bf, acc1[t], 0, 0, 0);
    }
  }

  // ---- relu + stage -> A layout for GEMM3 ----
  short8 a3[2][4];
  #pragma unroll
  for (int nn2 = 0; nn2 < 2; nn2++) {
    f32x4* ac = nn2 ? acc1 : acc0;
    #pragma unroll
    for (int t = 0; t < 8; t++) {
      int c = 16 * t + l15;
      float bb = ba1[c];
      uint32_t p01 = pk_bf16(fmaxf(ac[t][0] + bb, 0.f), fmaxf(ac[t][1] + bb, 0.f));
      uint32_t p23 = pk_bf16(fmaxf(ac[t][2] + bb, 0.f), fmaxf(ac[t][3] + bb, 0.f));
      stg[w][(quad * 4 + 0) * PES + c] = (unsigned short)p01;
      stg[w][(quad * 4 + 1) * PES + c] = (unsigned short)(p01 >> 16);
      stg[w][(quad * 4 + 2) * PES + c] = (unsigned short)p23;
      stg[w][(quad * 4 + 3) * PES + c] = (unsigned short)(p23 >> 16);
    }
    #pragma unroll
    for (int s = 0; s < 4; s++)
      a3[nn2][s] = *reinterpret_cast<const short8*>(&stg[w][l15 * PES + 32 * s + quad * 8]);
  }

  // ---- GEMM3: attn = hidden @ Wa2 + ba2 ----
  #pragma unroll
  for (int t = 0; t < 8; t++) { acc0[t] = (f32x4){0,0,0,0}; acc1[t] = (f32x4){0,0,0,0}; }
  #pragma unroll
  for (int s = 0; s < 4; s++) {
    #pragma unroll
    for (int t = 0; t < 8; t++) {
      short8 bf = *reinterpret_cast<const short8*>(sB + 32768 + ((t * 4 + s) * 64 + lane) * 8);
      acc0[t] = __builtin_amdgcn_mfma_f32_16x16x32_bf16(a3[0][s], bf, acc0[t], 0, 0, 0);
      acc1[t] = __builtin_amdgcn_mfma_f32_16x16x32_bf16(a3[1][s], bf, acc1[t], 0, 0, 0);
    }
  }

  // ---- softmax over K=16 + aggregation (pe from regs; C/D layouts match) ----
  int vb[2][4];
  #pragma unroll
  for (int nn2 = 0; nn2 < 2; nn2++)
    #pragma unroll
    for (int r = 0; r < 4; r++)
      vb[nn2][r] = sidx[w][nn2][quad * 4 + r] * 128;

  #pragma unroll
  for (int t = 0; t < 8; t++) {
    int c = 16 * t + l15;
    float bb = ba2[c];
    #pragma unroll
    for (int nn2 = 0; nn2 < 2; nn2++) {
      f32x4* ac = nn2 ? acc1 : acc0;
      float g0 = ac[t][0] + bb, g1 = ac[t][1] + bb;
      float g2 = ac[t][2] + bb, g3 = ac[t][3] + bb;
      float mx = fmaxf(fmaxf(g0, g1), fmaxf(g2, g3));
      mx = fmaxf(mx, __shfl_xor(mx, 16));
      mx = fmaxf(mx, __shfl_xor(mx, 32));
      float e0 = __expf(g0 - mx), e1 = __expf(g1 - mx);
      float e2 = __expf(g2 - mx), e3 = __expf(g3 - mx);
      float ls = e0 + e1 + e2 + e3;
      ls += __shfl_xor(ls, 16);
      ls += __shfl_xor(ls, 32);
      float pe0 = lo_f(pe_pk[nn2][t][0]), pe1 = hi_f(pe_pk[nn2][t][0]);
      float pe2 = lo_f(pe_pk[nn2][t][1]), pe3 = hi_f(pe_pk[nn2][t][1]);
      float p = e0 * (vg[vb[nn2][0] + c] + pe0)
              + e1 * (vg[vb[nn2][1] + c] + pe1)
              + e2 * (vg[vb[nn2][2] + c] + pe2)
              + e3 * (vg[vb[nn2][3] + c] + pe3);
      p += __shfl_xor(p, 16);
      p += __shfl_xor(p, 32);
      if (quad == 0) sagg[w * 2 + nn2][c] = p * __builtin_amdgcn_rcpf(ls);
    }
  }
  __syncthreads();   // barrier 2: sagg complete

  // ---- fused Wo: out = sagg @ Wo + bo. wave w handles tile t=w ----
  {
    short8 ah[4], al[4];
    #pragma unroll
    for (int s = 0; s < 4; s++) {
      f32x4 x0 = *reinterpret_cast<const f32x4*>(&sagg[l15][32 * s + quad * 8]);
      f32x4 x1 = *reinterpret_cast<const f32x4*>(&sagg[l15][32 * s + quad * 8 + 4]);
      split_frag(x0, x1, ah[s], al[s]);
    }
    f32x4 aw = {0.f, 0.f, 0.f, 0.f};
    #pragma unroll
    for (int s = 0; s < 4; s++) {
      short8 bh = *reinterpret_cast<const short8*>(fwoh + ((w * 4 + s) * 64 + lane) * 8);
      short8 bl = *reinterpret_cast<const short8*>(fwol + ((w * 4 + s) * 64 + lane) * 8);
      aw = __builtin_amdgcn_mfma_f32_16x16x32_bf16(ah[s], bh, aw, 0, 0, 0);
      aw = __builtin_amdgcn_mfma_f32_16x16x32_bf16(ah[s], bl, aw, 0, 0, 0);
      aw = __builtin_amdgcn_mfma_f32_16x16x32_bf16(al[s], bh, aw, 0, 0, 0);
    }
    int c = 16 * w + l15;
    float bb = bo[c];
    #pragma unroll
    for (int r = 0; r < 4; r++)
      out[(nb0 + quad * 4 + r) * 128 + c] = aw[r] + bb;
  }
}

extern "C" void kernel_launch(void* const* d_in, const int* in_sizes, int n_in,
                              void* d_out, int out_size, void* d_ws, size_t ws_size,
                              hipStream_t stream) {
  const float* x   = (const float*)d_in[0];
  const float* pos = (const float*)d_in[1];
  const int*   idx = (const int*)d_in[2];
  const float* Wq  = (const float*)d_in[3];
  const float* bq  = (const float*)d_in[4];
  const float* Wkv = (const float*)d_in[5];
  const float* bkv = (const float*)d_in[6];
  const float* Wp1 = (const float*)d_in[7];
  const float* bp1 = (const float*)d_in[8];
  const float* Wp2 = (const float*)d_in[9];
  const float* bp2 = (const float*)d_in[10];
  const float* Wa1 = (const float*)d_in[11];
  const float* ba1 = (const float*)d_in[12];
  const float* Wa2 = (const float*)d_in[13];
  const float* ba2 = (const float*)d_in[14];
  const float* Wo  = (const float*)d_in[15];
  const float* bo  = (const float*)d_in[16];

  char* ws = (char*)d_ws;
  short* fqh  = (short*)(ws + 0);
  short* fql  = (short*)(ws + 49152);
  short* fwp2 = (short*)(ws + 98304);     // fwp2|fwa1|fwa2 contiguous = fw_all
  short* fwa1 = (short*)(ws + 131072);
  short* fwa2 = (short*)(ws + 163840);
  short* fwoh = (short*)(ws + 196608);
  short* fwol = (short*)(ws + 229376);
  float* qb = (float*)(ws + 262144);
  float* kb = qb + NN_TOT * 128;
  float* vb = kb + NN_TOT * 128;

  prep_frags<<<44, 256, 0, stream>>>(Wq, Wkv, Wp2, Wa1, Wa2, Wo,
                                     fqh, fql, fwp2, fwa1, fwa2, fwoh, fwol);
  qkv_kernel<<<1536, 256, 0, stream>>>(x, bq, bkv, fqh, fql, qb, kb, vb);
  fused_attn_wo<<<1024, 512, 0, stream>>>(pos, idx, Wp1, bp1, bp2, ba1, ba2,
                                          fwp2, fwoh, fwol, bo,
                                          qb, kb, vb, (float*)d_out);
}

// Round 6
// 187.067 us; speedup vs baseline: 1.2504x; 1.0386x over previous
//
#include <hip/hip_runtime.h>
#include <stdint.h>

// ---------------------------------------------------------------------------
// MultiHeadPointAttention (B=2, N=8192, K=16, H=4, Cin=64, Cout=128, D=32)
//
//   prep_frags    : weights -> bf16 MFMA B-fragment layout in ws
//   qkv_kernel    : q(f32),k,v(bf16) = x @ [Wq|Wkv] + bias; per-block LDS B-slice
//   fused_attn_wo : block=512 (8 waves, 16 nodes, 2/wave), 70 KB LDS ->
//                   2 blocks/CU. Single 32 KB sB cycled Wp2->Wa1->Wa2 with 6
//                   barriers (hidden by the co-resident block). Wave-private
//                   stg for C/D->A transposes; sagg overlaid on stg; q folded
//                   into pe-stage (C/D layout); k gathered as packed bf16.
//
// R5 lesson: 96 KB sB -> 1 block/CU -> 2 waves/SIMD -> 62% stall. Occupancy
// (2 blocks/CU) is worth more than barrier-free phasing.
//
// MFMA 16x16x32 bf16 layouts (HW-verified):
//   A[m][k]: m = lane&15, k = (lane>>4)*8 + j
//   B[k][n]: n = lane&15, k = (lane>>4)*8 + j
//   D[r][c]: c = lane&15, r = (lane>>4)*4 + reg
// ---------------------------------------------------------------------------

typedef __attribute__((ext_vector_type(8))) short short8;
typedef __attribute__((ext_vector_type(4))) float f32x4;
typedef __attribute__((ext_vector_type(4))) unsigned int u32x4;

#define NN_TOT 16384   // B*N
#define PES 136        // stage row stride in bf16 elems (16B-aligned)

__device__ __forceinline__ uint32_t pk_bf16(float a, float b) {
  uint32_t r;
  asm("v_cvt_pk_bf16_f32 %0, %1, %2" : "=v"(r) : "v"(a), "v"(b));
  return r;  // low = bf16(a), high = bf16(b)
}
__device__ __forceinline__ float lo_f(uint32_t p) {
  return __builtin_bit_cast(float, p << 16);
}
__device__ __forceinline__ float hi_f(uint32_t p) {
  return __builtin_bit_cast(float, p & 0xffff0000u);
}
__device__ __forceinline__ short f2bf_rne(float f) {   // prep only
  uint32_t u = __builtin_bit_cast(uint32_t, f);
  uint32_t r = (u + 0x7FFFu + ((u >> 16) & 1u)) >> 16;
  return (short)r;
}
__device__ __forceinline__ float bf2f(unsigned short s) {
  uint32_t u = ((uint32_t)s) << 16;
  return __builtin_bit_cast(float, u);
}

__global__ __launch_bounds__(256) void prep_frags(
    const float* __restrict__ Wq, const float* __restrict__ Wkv,
    const float* __restrict__ Wp2, const float* __restrict__ Wa1,
    const float* __restrict__ Wa2, const float* __restrict__ Wo,
    short* __restrict__ fqh, short* __restrict__ fql,
    short* __restrict__ fwp2, short* __restrict__ fwa1, short* __restrict__ fwa2,
    short* __restrict__ fwoh, short* __restrict__ fwol) {
  int r = blockIdx.x * 256 + threadIdx.x;   // grid = 44*256 = 11264 exact
  if (r < 3072) {
    int t = r >> 7, rem = r & 127, s = rem >> 6, lane = rem & 63;
    int quad = lane >> 4, l15 = lane & 15;
    int col = t * 16 + l15;
    #pragma unroll
    for (int j = 0; j < 8; j++) {
      int i = 32 * s + quad * 8 + j;
      float wv = (col < 128) ? Wq[i * 128 + col] : Wkv[i * 256 + (col - 128)];
      short hi = f2bf_rne(wv);
      fqh[r * 8 + j] = hi;
      fql[r * 8 + j] = f2bf_rne(wv - bf2f((unsigned short)hi));
    }
  } else {
    int r2 = r - 3072;
    int mat = r2 >> 11;        // 0:Wp2 1:Wa1 2:Wa2 3:Wo
    int rr = r2 & 2047;
    int t = rr >> 8, rem = rr & 255, s = rem >> 6, lane = rem & 63;
    int quad = lane >> 4, l15 = lane & 15;
    int col = t * 16 + l15;
    const float* W = (mat == 0) ? Wp2 : (mat == 1) ? Wa1 : (mat == 2) ? Wa2 : Wo;
    #pragma unroll
    for (int j = 0; j < 8; j++) {
      int i = 32 * s + quad * 8 + j;
      float wv = W[i * 128 + col];
      short hi = f2bf_rne(wv);
      if (mat == 3) {
        fwoh[rr * 8 + j] = hi;
        fwol[rr * 8 + j] = f2bf_rne(wv - bf2f((unsigned short)hi));
      } else if (mat == 0) fwp2[rr * 8 + j] = hi;
      else if (mat == 1)   fwa1[rr * 8 + j] = hi;
      else                 fwa2[rr * 8 + j] = hi;
    }
  }
}

__device__ __forceinline__ void split_frag(const f32x4 x0, const f32x4 x1,
                                           short8& ah, short8& al) {
  uint32_t h01 = pk_bf16(x0[0], x0[1]);
  uint32_t h23 = pk_bf16(x0[2], x0[3]);
  uint32_t h45 = pk_bf16(x1[0], x1[1]);
  uint32_t h67 = pk_bf16(x1[2], x1[3]);
  u32x4 hh = {h01, h23, h45, h67};
  ah = __builtin_bit_cast(short8, hh);
  uint32_t l01 = pk_bf16(x0[0] - lo_f(h01), x0[1] - hi_f(h01));
  uint32_t l23 = pk_bf16(x0[2] - lo_f(h23), x0[3] - hi_f(h23));
  uint32_t l45 = pk_bf16(x1[0] - lo_f(h45), x1[1] - hi_f(h45));
  uint32_t l67 = pk_bf16(x1[2] - lo_f(h67), x1[3] - hi_f(h67));
  u32x4 ll = {l01, l23, l45, l67};
  al = __builtin_bit_cast(short8, ll);
}

// ---------------------------------------------------------------------------
// q,k,v projection. Block = 256 thr (4 waves), all waves share one section
// (0=q f32, 1=k bf16, 2=v bf16); the section's B-slice (32 KB hi+lo) is
// staged in LDS. Grid = 3 sections x 256 group-quads = 768 blocks.
// ---------------------------------------------------------------------------
__global__ __launch_bounds__(256) void qkv_kernel(
    const float* __restrict__ x, const float* __restrict__ bq,
    const float* __restrict__ bkv,
    const short* __restrict__ fqh, const short* __restrict__ fql,
    float* __restrict__ q, unsigned short* __restrict__ ko,
    unsigned short* __restrict__ vo) {
  __shared__ __align__(16) short sBq[16384];   // hi [0..8191], lo [8192..16383]
  const int tid = threadIdx.x;
  const int sec = blockIdx.x >> 8;             // 0..2
  const int gq = blockIdx.x & 255;
  const int w = tid >> 6, lane = tid & 63;
  const int quad = lane >> 4, l15 = lane & 15;

  {  // stage 16 KB hi + 16 KB lo of this section's frag rows
    const u32x4* sh = reinterpret_cast<const u32x4*>(fqh + sec * 8192);
    const u32x4* sl = reinterpret_cast<const u32x4*>(fql + sec * 8192);
    u32x4* dh = reinterpret_cast<u32x4*>(sBq);
    u32x4* dl = reinterpret_cast<u32x4*>(sBq + 8192);
    #pragma unroll
    for (int i = 0; i < 4; i++) {
      dh[tid + i * 256] = sh[tid + i * 256];
      dl[tid + i * 256] = sl[tid + i * 256];
    }
  }

  const int base = (gq * 4 + w) * 16;
  short8 ah[2], al[2];
  #pragma unroll
  for (int s = 0; s < 2; s++) {
    const float* xp = x + (base + l15) * 64 + 32 * s + quad * 8;
    split_frag(*reinterpret_cast<const f32x4*>(xp),
               *reinterpret_cast<const f32x4*>(xp + 4), ah[s], al[s]);
  }
  __syncthreads();

  #pragma unroll
  for (int tt = 0; tt < 8; tt++) {
    f32x4 acc = {0.f, 0.f, 0.f, 0.f};
    #pragma unroll
    for (int s = 0; s < 2; s++) {
      int rt = tt * 2 + s;
      short8 bh = *reinterpret_cast<const short8*>(sBq + rt * 512 + lane * 8);
      short8 bl = *reinterpret_cast<const short8*>(sBq + 8192 + rt * 512 + lane * 8);
      acc = __builtin_amdgcn_mfma_f32_16x16x32_bf16(ah[s], bh, acc, 0, 0, 0);
      acc = __builtin_amdgcn_mfma_f32_16x16x32_bf16(ah[s], bl, acc, 0, 0, 0);
      acc = __builtin_amdgcn_mfma_f32_16x16x32_bf16(al[s], bh, acc, 0, 0, 0);
    }
    int cl = tt * 16 + l15;                       // column within section
    if (sec == 0) {
      float bias = bq[cl];
      #pragma unroll
      for (int r = 0; r < 4; r++)
        q[(base + quad * 4 + r) * 128 + cl] = acc[r] + bias;
    } else {
      float bias = bkv[(sec - 1) * 128 + cl];
      unsigned short* dst = (sec == 1) ? ko : vo;
      #pragma unroll
      for (int r = 0; r < 4; r++) {
        float vv = acc[r] + bias;
        dst[(base + quad * 4 + r) * 128 + cl] = (unsigned short)pk_bf16(vv, vv);
      }
    }
  }
}

// ---------------------------------------------------------------------------
// Fused attention + Wo. Block = 512 thr (8 waves), 16 nodes (2/wave), 70 KB
// LDS -> 2 blocks/CU. sB (32 KB) cycled through Wp2 / Wa1 / Wa2.
// ---------------------------------------------------------------------------
__global__ __launch_bounds__(512, 4) void fused_attn_wo(
    const float* __restrict__ pos, const int* __restrict__ idx,
    const float* __restrict__ Wp1, const float* __restrict__ bp1,
    const float* __restrict__ bp2, const float* __restrict__ ba1,
    const float* __restrict__ ba2,
    const short* __restrict__ fwp2, const short* __restrict__ fwa1,
    const short* __restrict__ fwa2,
    const short* __restrict__ fwoh, const short* __restrict__ fwol,
    const float* __restrict__ bo,
    const float* __restrict__ qg, const unsigned short* __restrict__ kg,
    const unsigned short* __restrict__ vg, float* __restrict__ out) {
  __shared__ __align__(16) short sB[16384];                 // 32 KB, cycled
  __shared__ __align__(16) unsigned short stg[8][16 * PES]; // 34.8 KB wave-private
  __shared__ float spd[8][2][16][3];
  __shared__ int sidx[8][2][16];
  float (*sagg)[132] = reinterpret_cast<float(*)[132]>(&stg[0][0]);  // union

  const int tid = threadIdx.x;
  const int w = tid >> 6;
  const int lane = tid & 63;
  const int quad = lane >> 4, l15 = lane & 15;
  const int nb0 = blockIdx.x * 16;
  const int nbw = nb0 + w * 2;

  // ---- neighbor idx + pos_diff (wave-private) ----
  if (lane < 32) {
    int nn2 = lane >> 4, m = lane & 15;
    int node = nbw + nn2;
    int ji = idx[node * 16 + m];
    int jn = ((node >> 13) << 13) + ji;
    sidx[w][nn2][m] = jn;
    spd[w][nn2][m][0] = pos[node * 3 + 0] - pos[jn * 3 + 0];
    spd[w][nn2][m][1] = pos[node * 3 + 1] - pos[jn * 3 + 1];
    spd[w][nn2][m][2] = pos[node * 3 + 2] - pos[jn * 3 + 2];
  }

  // ---- stage sB <- Wp2 frags (32 KB, all threads) ----
  {
    const u32x4* s4 = reinterpret_cast<const u32x4*>(fwp2);
    u32x4* d4 = reinterpret_cast<u32x4*>(sB);
    #pragma unroll
    for (int i = 0; i < 4; i++) d4[tid + i * 512] = s4[tid + i * 512];
  }

  // ---- pos MLP layer 1 -> stg -> aP A-frags (wave-private) ----
  short8 aP[2][4];
  {
    const int c0 = lane, c1 = lane + 64;
    float wp00 = Wp1[c0], wp01 = Wp1[128 + c0], wp02 = Wp1[256 + c0], bb0 = bp1[c0];
    float wp10 = Wp1[c1], wp11 = Wp1[128 + c1], wp12 = Wp1[256 + c1], bb1 = bp1[c1];
    #pragma unroll
    for (int nn2 = 0; nn2 < 2; nn2++) {
      #pragma unroll
      for (int m = 0; m < 16; m++) {
        float d0 = spd[w][nn2][m][0], d1 = spd[w][nn2][m][1], d2 = spd[w][nn2][m][2];
        float h0 = fmaxf(bb0 + d0 * wp00 + d1 * wp01 + d2 * wp02, 0.f);
        float h1 = fmaxf(bb1 + d0 * wp10 + d1 * wp11 + d2 * wp12, 0.f);
        uint32_t pck = pk_bf16(h0, h1);
        stg[w][m * PES + c0] = (unsigned short)pck;
        stg[w][m * PES + c1] = (unsigned short)(pck >> 16);
      }
      #pragma unroll
      for (int s = 0; s < 4; s++)
        aP[nn2][s] = *reinterpret_cast<const short8*>(&stg[w][l15 * PES + 32 * s + quad * 8]);
    }
  }
  __syncthreads();   // barrier 1: sB = Wp2 ready

  // ---- issue k gathers (packed bf16; latency hides under GEMM1) ----
  short8 k_pk[2][4];
  #pragma unroll
  for (int nn2 = 0; nn2 < 2; nn2++) {
    const unsigned short* kp = kg + sidx[w][nn2][l15] * 128;
    #pragma unroll
    for (int s = 0; s < 4; s++)
      k_pk[nn2][s] = *reinterpret_cast<const short8*>(kp + 32 * s + quad * 8);
  }

  f32x4 acc0[8], acc1[8];

  // ---- GEMM1: pos_enc = pos_hidden @ Wp2 ----
  #pragma unroll
  for (int t = 0; t < 8; t++) { acc0[t] = (f32x4){0,0,0,0}; acc1[t] = (f32x4){0,0,0,0}; }
  #pragma unroll
  for (int s = 0; s < 4; s++) {
    #pragma unroll
    for (int t = 0; t < 8; t++) {
      short8 bf = *reinterpret_cast<const short8*>(sB + ((t * 4 + s) * 64 + lane) * 8);
      acc0[t] = __builtin_amdgcn_mfma_f32_16x16x32_bf16(aP[0][s], bf, acc0[t], 0, 0, 0);
      acc1[t] = __builtin_amdgcn_mfma_f32_16x16x32_bf16(aP[1][s], bf, acc1[t], 0, 0, 0);
    }
  }
  __syncthreads();   // barrier 2: all waves done reading Wp2

  // ---- restage sB <- Wa1 (overlaps with pe-stage below) ----
  {
    const u32x4* s4 = reinterpret_cast<const u32x4*>(fwa1);
    u32x4* d4 = reinterpret_cast<u32x4*>(sB);
    #pragma unroll
    for (int i = 0; i < 4; i++) d4[tid + i * 512] = s4[tid + i * 512];
  }

  // ---- pe = acc + bp2: keep packed pe; stage (pe - q) -> A layout ----
  uint32_t pe_pk[2][8][2];
  short8 a2[2][4];
  #pragma unroll
  for (int nn2 = 0; nn2 < 2; nn2++) {
    f32x4* ac = nn2 ? acc1 : acc0;
    const float* qrow = qg + (nbw + nn2) * 128;
    #pragma unroll
    for (int t = 0; t < 8; t++) {
      int c = 16 * t + l15;
      float bb = bp2[c];
      float qv = qrow[c];                 // q in C/D layout: one scalar per t
      float f0 = ac[t][0] + bb, f1 = ac[t][1] + bb;
      float f2 = ac[t][2] + bb, f3 = ac[t][3] + bb;
      pe_pk[nn2][t][0] = pk_bf16(f0, f1);
      pe_pk[nn2][t][1] = pk_bf16(f2, f3);
      uint32_t g01 = pk_bf16(f0 - qv, f1 - qv);
      uint32_t g23 = pk_bf16(f2 - qv, f3 - qv);
      stg[w][(quad * 4 + 0) * PES + c] = (unsigned short)g01;
      stg[w][(quad * 4 + 1) * PES + c] = (unsigned short)(g01 >> 16);
      stg[w][(quad * 4 + 2) * PES + c] = (unsigned short)g23;
      stg[w][(quad * 4 + 3) * PES + c] = (unsigned short)(g23 >> 16);
    }
    #pragma unroll
    for (int s = 0; s < 4; s++) {
      short8 pq = *reinterpret_cast<const short8*>(&stg[w][l15 * PES + 32 * s + quad * 8]);
      short8 kk = k_pk[nn2][s];
      u32x4 av = {pk_bf16(bf2f((unsigned short)kk[0]) + bf2f((unsigned short)pq[0]),
                          bf2f((unsigned short)kk[1]) + bf2f((unsigned short)pq[1])),
                  pk_bf16(bf2f((unsigned short)kk[2]) + bf2f((unsigned short)pq[2]),
                          bf2f((unsigned short)kk[3]) + bf2f((unsigned short)pq[3])),
                  pk_bf16(bf2f((unsigned short)kk[4]) + bf2f((unsigned short)pq[4]),
                          bf2f((unsigned short)kk[5]) + bf2f((unsigned short)pq[5])),
                  pk_bf16(bf2f((unsigned short)kk[6]) + bf2f((unsigned short)pq[6]),
                          bf2f((unsigned short)kk[7]) + bf2f((unsigned short)pq[7]))};
      a2[nn2][s] = __builtin_bit_cast(short8, av);
    }
  }
  __syncthreads();   // barrier 3: sB = Wa1 ready

  // ---- GEMM2: hidden = relu(rel @ Wa1 + ba1) ----
  #pragma unroll
  for (int t = 0; t < 8; t++) { acc0[t] = (f32x4){0,0,0,0}; acc1[t] = (f32x4){0,0,0,0}; }
  #pragma unroll
  for (int s = 0; s < 4; s++) {
    #pragma unroll
    for (int t = 0; t < 8; t++) {
      short8 bf = *reinterpret_cast<const short8*>(sB + ((t * 4 + s) * 64 + lane) * 8);
      acc0[t] = __builtin_amdgcn_mfma_f32_16x16x32_bf16(a2[0][s], bf, acc0[t], 0, 0, 0);
      acc1[t] = __builtin_amdgcn_mfma_f32_16x16x32_bf16(a2[1][s], bf, acc1[t], 0, 0, 0);
    }
  }
  __syncthreads();   // barrier 4: all waves done reading Wa1

  // ---- restage sB <- Wa2 (overlaps relu-stage below) ----
  {
    const u32x4* s4 = reinterpret_cast<const u32x4*>(fwa2);
    u32x4* d4 = reinterpret_cast<u32x4*>(sB);
    #pragma unroll
    for (int i = 0; i < 4; i++) d4[tid + i * 512] = s4[tid + i * 512];
  }

  // ---- relu + ba1 -> stg -> a3 A-frags ----
  short8 a3[2][4];
  #pragma unroll
  for (int nn2 = 0; nn2 < 2; nn2++) {
    f32x4* ac = nn2 ? acc1 : acc0;
    #pragma unroll
    for (int t = 0; t < 8; t++) {
      int c = 16 * t + l15;
      float bb = ba1[c];
      uint32_t p01 = pk_bf16(fmaxf(ac[t][0] + bb, 0.f), fmaxf(ac[t][1] + bb, 0.f));
      uint32_t p23 = pk_bf16(fmaxf(ac[t][2] + bb, 0.f), fmaxf(ac[t][3] + bb, 0.f));
      stg[w][(quad * 4 + 0) * PES + c] = (unsigned short)p01;
      stg[w][(quad * 4 + 1) * PES + c] = (unsigned short)(p01 >> 16);
      stg[w][(quad * 4 + 2) * PES + c] = (unsigned short)p23;
      stg[w][(quad * 4 + 3) * PES + c] = (unsigned short)(p23 >> 16);
    }
    #pragma unroll
    for (int s = 0; s < 4; s++)
      a3[nn2][s] = *reinterpret_cast<const short8*>(&stg[w][l15 * PES + 32 * s + quad * 8]);
  }
  __syncthreads();   // barrier 5: sB = Wa2 ready; all stg reads done (sagg safe)

  // ---- GEMM3: attn = hidden @ Wa2 + ba2 ----
  #pragma unroll
  for (int t = 0; t < 8; t++) { acc0[t] = (f32x4){0,0,0,0}; acc1[t] = (f32x4){0,0,0,0}; }
  #pragma unroll
  for (int s = 0; s < 4; s++) {
    #pragma unroll
    for (int t = 0; t < 8; t++) {
      short8 bf = *reinterpret_cast<const short8*>(sB + ((t * 4 + s) * 64 + lane) * 8);
      acc0[t] = __builtin_amdgcn_mfma_f32_16x16x32_bf16(a3[0][s], bf, acc0[t], 0, 0, 0);
      acc1[t] = __builtin_amdgcn_mfma_f32_16x16x32_bf16(a3[1][s], bf, acc1[t], 0, 0, 0);
    }
  }

  // ---- softmax over K=16 + aggregation (v bf16 gathers, pe from regs) ----
  int vb[2][4];
  #pragma unroll
  for (int nn2 = 0; nn2 < 2; nn2++)
    #pragma unroll
    for (int r = 0; r < 4; r++)
      vb[nn2][r] = sidx[w][nn2][quad * 4 + r] * 128;

  #pragma unroll
  for (int t = 0; t < 8; t++) {
    int c = 16 * t + l15;
    float bb = ba2[c];
    #pragma unroll
    for (int nn2 = 0; nn2 < 2; nn2++) {
      f32x4* ac = nn2 ? acc1 : acc0;
      float g0 = ac[t][0] + bb, g1 = ac[t][1] + bb;
      float g2 = ac[t][2] + bb, g3 = ac[t][3] + bb;
      float mx = fmaxf(fmaxf(g0, g1), fmaxf(g2, g3));
      mx = fmaxf(mx, __shfl_xor(mx, 16));
      mx = fmaxf(mx, __shfl_xor(mx, 32));
      float e0 = __expf(g0 - mx), e1 = __expf(g1 - mx);
      float e2 = __expf(g2 - mx), e3 = __expf(g3 - mx);
      float ls = e0 + e1 + e2 + e3;
      ls += __shfl_xor(ls, 16);
      ls += __shfl_xor(ls, 32);
      float pe0 = lo_f(pe_pk[nn2][t][0]), pe1 = hi_f(pe_pk[nn2][t][0]);
      float pe2 = lo_f(pe_pk[nn2][t][1]), pe3 = hi_f(pe_pk[nn2][t][1]);
      float p = e0 * (bf2f(vg[vb[nn2][0] + c]) + pe0)
              + e1 * (bf2f(vg[vb[nn2][1] + c]) + pe1)
              + e2 * (bf2f(vg[vb[nn2][2] + c]) + pe2)
              + e3 * (bf2f(vg[vb[nn2][3] + c]) + pe3);
      p += __shfl_xor(p, 16);
      p += __shfl_xor(p, 32);
      if (quad == 0) sagg[w * 2 + nn2][c] = p * __builtin_amdgcn_rcpf(ls);
    }
  }
  __syncthreads();   // barrier 6: sagg complete

  // ---- fused Wo: out = sagg @ Wo + bo (wave w = output tile w) ----
  {
    short8 ah[4], al[4];
    #pragma unroll
    for (int s = 0; s < 4; s++) {
      f32x4 x0 = *reinterpret_cast<const f32x4*>(&sagg[l15][32 * s + quad * 8]);
      f32x4 x1 = *reinterpret_cast<const f32x4*>(&sagg[l15][32 * s + quad * 8 + 4]);
      split_frag(x0, x1, ah[s], al[s]);
    }
    f32x4 aw = {0.f, 0.f, 0.f, 0.f};
    #pragma unroll
    for (int s = 0; s < 4; s++) {
      short8 bh = *reinterpret_cast<const short8*>(fwoh + ((w * 4 + s) * 64 + lane) * 8);
      short8 bl = *reinterpret_cast<const short8*>(fwol + ((w * 4 + s) * 64 + lane) * 8);
      aw = __builtin_amdgcn_mfma_f32_16x16x32_bf16(ah[s], bh, aw, 0, 0, 0);
      aw = __builtin_amdgcn_mfma_f32_16x16x32_bf16(ah[s], bl, aw, 0, 0, 0);
      aw = __builtin_amdgcn_mfma_f32_16x16x32_bf16(al[s], bh, aw, 0, 0, 0);
    }
    int c = 16 * w + l15;
    float bb = bo[c];
    #pragma unroll
    for (int r = 0; r < 4; r++)
      out[(nb0 + quad * 4 + r) * 128 + c] = aw[r] + bb;
  }
}

extern "C" void kernel_launch(void* const* d_in, const int* in_sizes, int n_in,
                              void* d_out, int out_size, void* d_ws, size_t ws_size,
                              hipStream_t stream) {
  const float* x   = (const float*)d_in[0];
  const float* pos = (const float*)d_in[1];
  const int*   idx = (const int*)d_in[2];
  const float* Wq  = (const float*)d_in[3];
  const float* bq  = (const float*)d_in[4];
  const float* Wkv = (const float*)d_in[5];
  const float* bkv = (const float*)d_in[6];
  const float* Wp1 = (const float*)d_in[7];
  const float* bp1 = (const float*)d_in[8];
  const float* Wp2 = (const float*)d_in[9];
  const float* bp2 = (const float*)d_in[10];
  const float* Wa1 = (const float*)d_in[11];
  const float* ba1 = (const float*)d_in[12];
  const float* Wa2 = (const float*)d_in[13];
  const float* ba2 = (const float*)d_in[14];
  const float* Wo  = (const float*)d_in[15];
  const float* bo  = (const float*)d_in[16];

  char* ws = (char*)d_ws;
  short* fqh  = (short*)(ws + 0);
  short* fql  = (short*)(ws + 49152);
  short* fwp2 = (short*)(ws + 98304);
  short* fwa1 = (short*)(ws + 131072);
  short* fwa2 = (short*)(ws + 163840);
  short* fwoh = (short*)(ws + 196608);
  short* fwol = (short*)(ws + 229376);
  float* qb = (float*)(ws + 262144);                          // 8 MB f32
  unsigned short* kb = (unsigned short*)(ws + 262144 + 8388608);   // 4 MB bf16
  unsigned short* vb = kb + NN_TOT * 128;                          // 4 MB bf16

  prep_frags<<<44, 256, 0, stream>>>(Wq, Wkv, Wp2, Wa1, Wa2, Wo,
                                     fqh, fql, fwp2, fwa1, fwa2, fwoh, fwol);
  qkv_kernel<<<768, 256, 0, stream>>>(x, bq, bkv, fqh, fql, qb, kb, vb);
  fused_attn_wo<<<1024, 512, 0, stream>>>(pos, idx, Wp1, bp1, bp2, ba1, ba2,
                                          fwp2, fwa1, fwa2, fwoh, fwol, bo,
                                          qb, kb, vb, (float*)d_out);
}

// Round 7
// 177.867 us; speedup vs baseline: 1.3151x; 1.0517x over previous
//
#include <hip/hip_runtime.h>
#include <stdint.h>

// ---------------------------------------------------------------------------
// MultiHeadPointAttention (B=2, N=8192, K=16, H=4, Cin=64, Cout=128, D=32)
//
//   prep_frags    : weights -> bf16 MFMA B-fragment layout in ws
//   qkv_kernel    : q(f32),k,v(bf16) = x @ [Wq|Wkv] + bias; per-block LDS B-slice
//   fused_attn_wo : block=512 (8 waves), ONE node per wave (NPW=1), 70 KB LDS
//                   -> 2 blocks/CU. 32 KB sB cycled Wp2->Wa1->Wa2, 6 barriers.
//                   Wo fused (8-valid-row 16x16 tile; D rows depend only on
//                   matching A rows, so garbage rows are simply not written).
//
// R6 lesson: NPW=2 under __launch_bounds__(512,4) (128-reg unified cap) needs
// 64 AGPR acc + >64 arch VGPR -> compiler spilled ~14 KB/wave to scratch
// (WRITE_SIZE 8->39->117 MB as caps tightened). NPW=1 halves all live state:
// acc=32 AGPR, pe_pk/k_pk 16 dw each -> fits spill-free.
//
// MFMA 16x16x32 bf16 layouts (HW-verified):
//   A[m][k]: m = lane&15, k = (lane>>4)*8 + j
//   B[k][n]: n = lane&15, k = (lane>>4)*8 + j
//   D[r][c]: c = lane&15, r = (lane>>4)*4 + reg
// ---------------------------------------------------------------------------

typedef __attribute__((ext_vector_type(8))) short short8;
typedef __attribute__((ext_vector_type(4))) float f32x4;
typedef __attribute__((ext_vector_type(4))) unsigned int u32x4;

#define NN_TOT 16384   // B*N
#define PES 136        // stage row stride in bf16 elems (16B-aligned)

__device__ __forceinline__ uint32_t pk_bf16(float a, float b) {
  uint32_t r;
  asm("v_cvt_pk_bf16_f32 %0, %1, %2" : "=v"(r) : "v"(a), "v"(b));
  return r;  // low = bf16(a), high = bf16(b)
}
__device__ __forceinline__ float lo_f(uint32_t p) {
  return __builtin_bit_cast(float, p << 16);
}
__device__ __forceinline__ float hi_f(uint32_t p) {
  return __builtin_bit_cast(float, p & 0xffff0000u);
}
__device__ __forceinline__ short f2bf_rne(float f) {   // prep only
  uint32_t u = __builtin_bit_cast(uint32_t, f);
  uint32_t r = (u + 0x7FFFu + ((u >> 16) & 1u)) >> 16;
  return (short)r;
}
__device__ __forceinline__ float bf2f(unsigned short s) {
  uint32_t u = ((uint32_t)s) << 16;
  return __builtin_bit_cast(float, u);
}

__global__ __launch_bounds__(256) void prep_frags(
    const float* __restrict__ Wq, const float* __restrict__ Wkv,
    const float* __restrict__ Wp2, const float* __restrict__ Wa1,
    const float* __restrict__ Wa2, const float* __restrict__ Wo,
    short* __restrict__ fqh, short* __restrict__ fql,
    short* __restrict__ fwp2, short* __restrict__ fwa1, short* __restrict__ fwa2,
    short* __restrict__ fwoh, short* __restrict__ fwol) {
  int r = blockIdx.x * 256 + threadIdx.x;   // grid = 44*256 = 11264 exact
  if (r < 3072) {
    int t = r >> 7, rem = r & 127, s = rem >> 6, lane = rem & 63;
    int quad = lane >> 4, l15 = lane & 15;
    int col = t * 16 + l15;
    #pragma unroll
    for (int j = 0; j < 8; j++) {
      int i = 32 * s + quad * 8 + j;
      float wv = (col < 128) ? Wq[i * 128 + col] : Wkv[i * 256 + (col - 128)];
      short hi = f2bf_rne(wv);
      fqh[r * 8 + j] = hi;
      fql[r * 8 + j] = f2bf_rne(wv - bf2f((unsigned short)hi));
    }
  } else {
    int r2 = r - 3072;
    int mat = r2 >> 11;        // 0:Wp2 1:Wa1 2:Wa2 3:Wo
    int rr = r2 & 2047;
    int t = rr >> 8, rem = rr & 255, s = rem >> 6, lane = rem & 63;
    int quad = lane >> 4, l15 = lane & 15;
    int col = t * 16 + l15;
    const float* W = (mat == 0) ? Wp2 : (mat == 1) ? Wa1 : (mat == 2) ? Wa2 : Wo;
    #pragma unroll
    for (int j = 0; j < 8; j++) {
      int i = 32 * s + quad * 8 + j;
      float wv = W[i * 128 + col];
      short hi = f2bf_rne(wv);
      if (mat == 3) {
        fwoh[rr * 8 + j] = hi;
        fwol[rr * 8 + j] = f2bf_rne(wv - bf2f((unsigned short)hi));
      } else if (mat == 0) fwp2[rr * 8 + j] = hi;
      else if (mat == 1)   fwa1[rr * 8 + j] = hi;
      else                 fwa2[rr * 8 + j] = hi;
    }
  }
}

__device__ __forceinline__ void split_frag(const f32x4 x0, const f32x4 x1,
                                           short8& ah, short8& al) {
  uint32_t h01 = pk_bf16(x0[0], x0[1]);
  uint32_t h23 = pk_bf16(x0[2], x0[3]);
  uint32_t h45 = pk_bf16(x1[0], x1[1]);
  uint32_t h67 = pk_bf16(x1[2], x1[3]);
  u32x4 hh = {h01, h23, h45, h67};
  ah = __builtin_bit_cast(short8, hh);
  uint32_t l01 = pk_bf16(x0[0] - lo_f(h01), x0[1] - hi_f(h01));
  uint32_t l23 = pk_bf16(x0[2] - lo_f(h23), x0[3] - hi_f(h23));
  uint32_t l45 = pk_bf16(x1[0] - lo_f(h45), x1[1] - hi_f(h45));
  uint32_t l67 = pk_bf16(x1[2] - lo_f(h67), x1[3] - hi_f(h67));
  u32x4 ll = {l01, l23, l45, l67};
  al = __builtin_bit_cast(short8, ll);
}

// ---------------------------------------------------------------------------
// q,k,v projection. Block = 256 thr (4 waves), one section per block
// (0=q f32, 1=k bf16, 2=v bf16); section B-slice (32 KB hi+lo) in LDS.
// ---------------------------------------------------------------------------
__global__ __launch_bounds__(256) void qkv_kernel(
    const float* __restrict__ x, const float* __restrict__ bq,
    const float* __restrict__ bkv,
    const short* __restrict__ fqh, const short* __restrict__ fql,
    float* __restrict__ q, unsigned short* __restrict__ ko,
    unsigned short* __restrict__ vo) {
  __shared__ __align__(16) short sBq[16384];   // hi [0..8191], lo [8192..16383]
  const int tid = threadIdx.x;
  const int sec = blockIdx.x >> 8;             // 0..2
  const int gq = blockIdx.x & 255;
  const int w = tid >> 6, lane = tid & 63;
  const int quad = lane >> 4, l15 = lane & 15;

  {  // stage 16 KB hi + 16 KB lo of this section's frag rows
    const u32x4* sh = reinterpret_cast<const u32x4*>(fqh + sec * 8192);
    const u32x4* sl = reinterpret_cast<const u32x4*>(fql + sec * 8192);
    u32x4* dh = reinterpret_cast<u32x4*>(sBq);
    u32x4* dl = reinterpret_cast<u32x4*>(sBq + 8192);
    #pragma unroll
    for (int i = 0; i < 4; i++) {
      dh[tid + i * 256] = sh[tid + i * 256];
      dl[tid + i * 256] = sl[tid + i * 256];
    }
  }

  const int base = (gq * 4 + w) * 16;
  short8 ah[2], al[2];
  #pragma unroll
  for (int s = 0; s < 2; s++) {
    const float* xp = x + (base + l15) * 64 + 32 * s + quad * 8;
    split_frag(*reinterpret_cast<const f32x4*>(xp),
               *reinterpret_cast<const f32x4*>(xp + 4), ah[s], al[s]);
  }
  __syncthreads();

  #pragma unroll
  for (int tt = 0; tt < 8; tt++) {
    f32x4 acc = {0.f, 0.f, 0.f, 0.f};
    #pragma unroll
    for (int s = 0; s < 2; s++) {
      int rt = tt * 2 + s;
      short8 bh = *reinterpret_cast<const short8*>(sBq + rt * 512 + lane * 8);
      short8 bl = *reinterpret_cast<const short8*>(sBq + 8192 + rt * 512 + lane * 8);
      acc = __builtin_amdgcn_mfma_f32_16x16x32_bf16(ah[s], bh, acc, 0, 0, 0);
      acc = __builtin_amdgcn_mfma_f32_16x16x32_bf16(ah[s], bl, acc, 0, 0, 0);
      acc = __builtin_amdgcn_mfma_f32_16x16x32_bf16(al[s], bh, acc, 0, 0, 0);
    }
    int cl = tt * 16 + l15;                       // column within section
    if (sec == 0) {
      float bias = bq[cl];
      #pragma unroll
      for (int r = 0; r < 4; r++)
        q[(base + quad * 4 + r) * 128 + cl] = acc[r] + bias;
    } else {
      float bias = bkv[(sec - 1) * 128 + cl];
      unsigned short* dst = (sec == 1) ? ko : vo;
      #pragma unroll
      for (int r = 0; r < 4; r++) {
        float vv = acc[r] + bias;
        dst[(base + quad * 4 + r) * 128 + cl] = (unsigned short)pk_bf16(vv, vv);
      }
    }
  }
}

// ---------------------------------------------------------------------------
// Fused attention + Wo. Block = 512 thr (8 waves), 8 nodes (1/wave), 70 KB
// LDS -> 2 blocks/CU. sB (32 KB) cycled Wp2 / Wa1 / Wa2.
// ---------------------------------------------------------------------------
__global__ __launch_bounds__(512, 4) void fused_attn_wo(
    const float* __restrict__ pos, const int* __restrict__ idx,
    const float* __restrict__ Wp1, const float* __restrict__ bp1,
    const float* __restrict__ bp2, const float* __restrict__ ba1,
    const float* __restrict__ ba2,
    const short* __restrict__ fwp2, const short* __restrict__ fwa1,
    const short* __restrict__ fwa2,
    const short* __restrict__ fwoh, const short* __restrict__ fwol,
    const float* __restrict__ bo,
    const float* __restrict__ qg, const unsigned short* __restrict__ kg,
    const unsigned short* __restrict__ vg, float* __restrict__ out) {
  __shared__ __align__(16) short sB[16384];                 // 32 KB, cycled
  __shared__ __align__(16) unsigned short stg[8][16 * PES]; // 34.8 KB wave-private
  __shared__ float spd[8][16][3];
  __shared__ int sidx[8][16];
  // sagg overlays stg[0..1] slabs: 16 rows x 132 floats = 8448 B. All stg
  // reads complete before barrier 5; sagg writes happen after it. Rows 8-15
  // are stale garbage, only rows 0-7 are written to out (D rows depend only
  // on matching A rows).
  float (*sagg)[132] = reinterpret_cast<float(*)[132]>(&stg[0][0]);

  const int tid = threadIdx.x;
  const int w = tid >> 6;
  const int lane = tid & 63;
  const int quad = lane >> 4, l15 = lane & 15;
  const int nb0 = blockIdx.x * 8;
  const int node = nb0 + w;

  // ---- neighbor idx + pos_diff (wave-private) ----
  if (lane < 16) {
    int ji = idx[node * 16 + lane];
    int jn = ((node >> 13) << 13) + ji;
    sidx[w][lane] = jn;
    spd[w][lane][0] = pos[node * 3 + 0] - pos[jn * 3 + 0];
    spd[w][lane][1] = pos[node * 3 + 1] - pos[jn * 3 + 1];
    spd[w][lane][2] = pos[node * 3 + 2] - pos[jn * 3 + 2];
  }

  // ---- stage sB <- Wp2 frags (32 KB, all threads) ----
  {
    const u32x4* s4 = reinterpret_cast<const u32x4*>(fwp2);
    u32x4* d4 = reinterpret_cast<u32x4*>(sB);
    #pragma unroll
    for (int i = 0; i < 4; i++) d4[tid + i * 512] = s4[tid + i * 512];
  }

  // ---- pos MLP layer 1 -> stg -> aP A-frags (wave-private) ----
  short8 aP[4];
  {
    const int c0 = lane, c1 = lane + 64;
    float wp00 = Wp1[c0], wp01 = Wp1[128 + c0], wp02 = Wp1[256 + c0], bb0 = bp1[c0];
    float wp10 = Wp1[c1], wp11 = Wp1[128 + c1], wp12 = Wp1[256 + c1], bb1 = bp1[c1];
    #pragma unroll
    for (int m = 0; m < 16; m++) {
      float d0 = spd[w][m][0], d1 = spd[w][m][1], d2 = spd[w][m][2];
      float h0 = fmaxf(bb0 + d0 * wp00 + d1 * wp01 + d2 * wp02, 0.f);
      float h1 = fmaxf(bb1 + d0 * wp10 + d1 * wp11 + d2 * wp12, 0.f);
      uint32_t pck = pk_bf16(h0, h1);
      stg[w][m * PES + c0] = (unsigned short)pck;
      stg[w][m * PES + c1] = (unsigned short)(pck >> 16);
    }
    #pragma unroll
    for (int s = 0; s < 4; s++)
      aP[s] = *reinterpret_cast<const short8*>(&stg[w][l15 * PES + 32 * s + quad * 8]);
  }
  __syncthreads();   // barrier 1: sB = Wp2 ready

  // ---- k gather (packed bf16; latency hides under GEMM1) ----
  short8 k_pk[4];
  {
    const unsigned short* kp = kg + sidx[w][l15] * 128;
    #pragma unroll
    for (int s = 0; s < 4; s++)
      k_pk[s] = *reinterpret_cast<const short8*>(kp + 32 * s + quad * 8);
  }

  f32x4 acc[8];

  // ---- GEMM1: pos_enc = pos_hidden @ Wp2 ----
  #pragma unroll
  for (int t = 0; t < 8; t++) acc[t] = (f32x4){0.f, 0.f, 0.f, 0.f};
  #pragma unroll
  for (int s = 0; s < 4; s++) {
    #pragma unroll
    for (int t = 0; t < 8; t++) {
      short8 bf = *reinterpret_cast<const short8*>(sB + ((t * 4 + s) * 64 + lane) * 8);
      acc[t] = __builtin_amdgcn_mfma_f32_16x16x32_bf16(aP[s], bf, acc[t], 0, 0, 0);
    }
  }
  __syncthreads();   // barrier 2: all waves done reading Wp2

  // ---- restage sB <- Wa1 (overlaps pe-stage below) ----
  {
    const u32x4* s4 = reinterpret_cast<const u32x4*>(fwa1);
    u32x4* d4 = reinterpret_cast<u32x4*>(sB);
    #pragma unroll
    for (int i = 0; i < 4; i++) d4[tid + i * 512] = s4[tid + i * 512];
  }

  // ---- pe = acc + bp2: keep packed pe; stage (pe - q) -> A layout ----
  uint32_t pe_pk[8][2];
  short8 a2[4];
  {
    const float* qrow = qg + node * 128;
    #pragma unroll
    for (int t = 0; t < 8; t++) {
      int c = 16 * t + l15;
      float bb = bp2[c];
      float qv = qrow[c];                 // q in C/D layout: one scalar per t
      float f0 = acc[t][0] + bb, f1 = acc[t][1] + bb;
      float f2 = acc[t][2] + bb, f3 = acc[t][3] + bb;
      pe_pk[t][0] = pk_bf16(f0, f1);
      pe_pk[t][1] = pk_bf16(f2, f3);
      uint32_t g01 = pk_bf16(f0 - qv, f1 - qv);
      uint32_t g23 = pk_bf16(f2 - qv, f3 - qv);
      stg[w][(quad * 4 + 0) * PES + c] = (unsigned short)g01;
      stg[w][(quad * 4 + 1) * PES + c] = (unsigned short)(g01 >> 16);
      stg[w][(quad * 4 + 2) * PES + c] = (unsigned short)g23;
      stg[w][(quad * 4 + 3) * PES + c] = (unsigned short)(g23 >> 16);
    }
    #pragma unroll
    for (int s = 0; s < 4; s++) {
      short8 pq = *reinterpret_cast<const short8*>(&stg[w][l15 * PES + 32 * s + quad * 8]);
      short8 kk = k_pk[s];
      u32x4 av = {pk_bf16(bf2f((unsigned short)kk[0]) + bf2f((unsigned short)pq[0]),
                          bf2f((unsigned short)kk[1]) + bf2f((unsigned short)pq[1])),
                  pk_bf16(bf2f((unsigned short)kk[2]) + bf2f((unsigned short)pq[2]),
                          bf2f((unsigned short)kk[3]) + bf2f((unsigned short)pq[3])),
                  pk_bf16(bf2f((unsigned short)kk[4]) + bf2f((unsigned short)pq[4]),
                          bf2f((unsigned short)kk[5]) + bf2f((unsigned short)pq[5])),
                  pk_bf16(bf2f((unsigned short)kk[6]) + bf2f((unsigned short)pq[6]),
                          bf2f((unsigned short)kk[7]) + bf2f((unsigned short)pq[7]))};
      a2[s] = __builtin_bit_cast(short8, av);
    }
  }
  __syncthreads();   // barrier 3: sB = Wa1 ready

  // ---- GEMM2: hidden = relu(rel @ Wa1 + ba1) ----
  #pragma unroll
  for (int t = 0; t < 8; t++) acc[t] = (f32x4){0.f, 0.f, 0.f, 0.f};
  #pragma unroll
  for (int s = 0; s < 4; s++) {
    #pragma unroll
    for (int t = 0; t < 8; t++) {
      short8 bf = *reinterpret_cast<const short8*>(sB + ((t * 4 + s) * 64 + lane) * 8);
      acc[t] = __builtin_amdgcn_mfma_f32_16x16x32_bf16(a2[s], bf, acc[t], 0, 0, 0);
    }
  }
  __syncthreads();   // barrier 4: all waves done reading Wa1

  // ---- restage sB <- Wa2 (overlaps relu-stage below) ----
  {
    const u32x4* s4 = reinterpret_cast<const u32x4*>(fwa2);
    u32x4* d4 = reinterpret_cast<u32x4*>(sB);
    #pragma unroll
    for (int i = 0; i < 4; i++) d4[tid + i * 512] = s4[tid + i * 512];
  }

  // ---- relu + ba1 -> stg -> a3 A-frags ----
  short8 a3[4];
  {
    #pragma unroll
    for (int t = 0; t < 8; t++) {
      int c = 16 * t + l15;
      float bb = ba1[c];
      uint32_t p01 = pk_bf16(fmaxf(acc[t][0] + bb, 0.f), fmaxf(acc[t][1] + bb, 0.f));
      uint32_t p23 = pk_bf16(fmaxf(acc[t][2] + bb, 0.f), fmaxf(acc[t][3] + bb, 0.f));
      stg[w][(quad * 4 + 0) * PES + c] = (unsigned short)p01;
      stg[w][(quad * 4 + 1) * PES + c] = (unsigned short)(p01 >> 16);
      stg[w][(quad * 4 + 2) * PES + c] = (unsigned short)p23;
      stg[w][(quad * 4 + 3) * PES + c] = (unsigned short)(p23 >> 16);
    }
    #pragma unroll
    for (int s = 0; s < 4; s++)
      a3[s] = *reinterpret_cast<const short8*>(&stg[w][l15 * PES + 32 * s + quad * 8]);
  }
  __syncthreads();   // barrier 5: sB = Wa2 ready; all stg reads done (sagg safe)

  // ---- GEMM3: attn = hidden @ Wa2 + ba2 ----
  #pragma unroll
  for (int t = 0; t < 8; t++) acc[t] = (f32x4){0.f, 0.f, 0.f, 0.f};
  #pragma unroll
  for (int s = 0; s < 4; s++) {
    #pragma unroll
    for (int t = 0; t < 8; t++) {
      short8 bf = *reinterpret_cast<const short8*>(sB + ((t * 4 + s) * 64 + lane) * 8);
      acc[t] = __builtin_amdgcn_mfma_f32_16x16x32_bf16(a3[s], bf, acc[t], 0, 0, 0);
    }
  }

  // ---- softmax over K=16 + aggregation (v bf16 gathers, pe from regs) ----
  int vb[4];
  #pragma unroll
  for (int r = 0; r < 4; r++) vb[r] = sidx[w][quad * 4 + r] * 128;

  #pragma unroll
  for (int t = 0; t < 8; t++) {
    int c = 16 * t + l15;
    float bb = ba2[c];
    float g0 = acc[t][0] + bb, g1 = acc[t][1] + bb;
    float g2 = acc[t][2] + bb, g3 = acc[t][3] + bb;
    float mx = fmaxf(fmaxf(g0, g1), fmaxf(g2, g3));
    mx = fmaxf(mx, __shfl_xor(mx, 16));
    mx = fmaxf(mx, __shfl_xor(mx, 32));
    float e0 = __expf(g0 - mx), e1 = __expf(g1 - mx);
    float e2 = __expf(g2 - mx), e3 = __expf(g3 - mx);
    float ls = e0 + e1 + e2 + e3;
    ls += __shfl_xor(ls, 16);
    ls += __shfl_xor(ls, 32);
    float pe0 = lo_f(pe_pk[t][0]), pe1 = hi_f(pe_pk[t][0]);
    float pe2 = lo_f(pe_pk[t][1]), pe3 = hi_f(pe_pk[t][1]);
    float p = e0 * (bf2f(vg[vb[0] + c]) + pe0)
            + e1 * (bf2f(vg[vb[1] + c]) + pe1)
            + e2 * (bf2f(vg[vb[2] + c]) + pe2)
            + e3 * (bf2f(vg[vb[3] + c]) + pe3);
    p += __shfl_xor(p, 16);
    p += __shfl_xor(p, 32);
    if (quad == 0) sagg[w][c] = p * __builtin_amdgcn_rcpf(ls);
  }
  __syncthreads();   // barrier 6: sagg rows 0-7 complete

  // ---- fused Wo: out = sagg @ Wo + bo (wave w = output tile w) ----
  {
    short8 ah[4], al[4];
    #pragma unroll
    for (int s = 0; s < 4; s++) {
      f32x4 x0 = *reinterpret_cast<const f32x4*>(&sagg[l15][32 * s + quad * 8]);
      f32x4 x1 = *reinterpret_cast<const f32x4*>(&sagg[l15][32 * s + quad * 8 + 4]);
      split_frag(x0, x1, ah[s], al[s]);
    }
    f32x4 aw = {0.f, 0.f, 0.f, 0.f};
    #pragma unroll
    for (int s = 0; s < 4; s++) {
      short8 bh = *reinterpret_cast<const short8*>(fwoh + ((w * 4 + s) * 64 + lane) * 8);
      short8 bl = *reinterpret_cast<const short8*>(fwol + ((w * 4 + s) * 64 + lane) * 8);
      aw = __builtin_amdgcn_mfma_f32_16x16x32_bf16(ah[s], bh, aw, 0, 0, 0);
      aw = __builtin_amdgcn_mfma_f32_16x16x32_bf16(ah[s], bl, aw, 0, 0, 0);
      aw = __builtin_amdgcn_mfma_f32_16x16x32_bf16(al[s], bh, aw, 0, 0, 0);
    }
    int c = 16 * w + l15;
    float bb = bo[c];
    if (quad < 2) {   // rows 0-7 valid (8 nodes/block)
      #pragma unroll
      for (int r = 0; r < 4; r++)
        out[(nb0 + quad * 4 + r) * 128 + c] = aw[r] + bb;
    }
  }
}

extern "C" void kernel_launch(void* const* d_in, const int* in_sizes, int n_in,
                              void* d_out, int out_size, void* d_ws, size_t ws_size,
                              hipStream_t stream) {
  const float* x   = (const float*)d_in[0];
  const float* pos = (const float*)d_in[1];
  const int*   idx = (const int*)d_in[2];
  const float* Wq  = (const float*)d_in[3];
  const float* bq  = (const float*)d_in[4];
  const float* Wkv = (const float*)d_in[5];
  const float* bkv = (const float*)d_in[6];
  const float* Wp1 = (const float*)d_in[7];
  const float* bp1 = (const float*)d_in[8];
  const float* Wp2 = (const float*)d_in[9];
  const float* bp2 = (const float*)d_in[10];
  const float* Wa1 = (const float*)d_in[11];
  const float* ba1 = (const float*)d_in[12];
  const float* Wa2 = (const float*)d_in[13];
  const float* ba2 = (const float*)d_in[14];
  const float* Wo  = (const float*)d_in[15];
  const float* bo  = (const float*)d_in[16];

  char* ws = (char*)d_ws;
  short* fqh  = (short*)(ws + 0);
  short* fql  = (short*)(ws + 49152);
  short* fwp2 = (short*)(ws + 98304);
  short* fwa1 = (short*)(ws + 131072);
  short* fwa2 = (short*)(ws + 163840);
  short* fwoh = (short*)(ws + 196608);
  short* fwol = (short*)(ws + 229376);
  float* qb = (float*)(ws + 262144);                               // 8 MB f32
  unsigned short* kb = (unsigned short*)(ws + 262144 + 8388608);   // 4 MB bf16
  unsigned short* vb = kb + NN_TOT * 128;                          // 4 MB bf16

  prep_frags<<<44, 256, 0, stream>>>(Wq, Wkv, Wp2, Wa1, Wa2, Wo,
                                     fqh, fql, fwp2, fwa1, fwa2, fwoh, fwol);
  qkv_kernel<<<768, 256, 0, stream>>>(x, bq, bkv, fqh, fql, qb, kb, vb);
  fused_attn_wo<<<2048, 512, 0, stream>>>(pos, idx, Wp1, bp1, bp2, ba1, ba2,
                                          fwp2, fwa1, fwa2, fwoh, fwol, bo,
                                          qb, kb, vb, (float*)d_out);
}

// Round 8
// 174.880 us; speedup vs baseline: 1.3376x; 1.0171x over previous
//
#include <hip/hip_runtime.h>
#include <stdint.h>

// ---------------------------------------------------------------------------
// MultiHeadPointAttention (B=2, N=8192, K=16, H=4, Cin=64, Cout=128, D=32)
//
//   prep_frags    : weights -> bf16 MFMA B-fragment layout in ws
//   qkv_kernel    : q(f32),k,v(bf16) = x @ [Wq|Wkv] + bias; per-block LDS B-slice
//   fused_attn_wo : block=512 (8 waves), NPW=1, 52.0 KB LDS -> 3 blocks/CU
//                   (24 waves/CU). 32 KB sB cycled Wp2->Wa1->Wa2, 6 barriers.
//                   C/D->A transposes through HALF-WIDTH per-wave slabs
//                   (16 rows x 72 shorts) in two column-phases (ch 0-63 then
//                   64-127): writes cols 16(t&3)+l15, reads s=2p..2p+1 —
//                   wave-private, intra-wave LDS ordering, no extra barriers.
//
// R7 lesson: 2 blocks/CU (69.6 KB) left ~49% stall; slabs were the LDS hog.
// R6 lesson: reg-cap overrun spills to scratch catastrophically (WRITE_SIZE
// is the tell). (512,6) caps at 85; R7's measured usage = 84 exactly.
//
// MFMA 16x16x32 bf16 layouts (HW-verified):
//   A[m][k]: m = lane&15, k = (lane>>4)*8 + j
//   B[k][n]: n = lane&15, k = (lane>>4)*8 + j
//   D[r][c]: c = lane&15, r = (lane>>4)*4 + reg
// ---------------------------------------------------------------------------

typedef __attribute__((ext_vector_type(8))) short short8;
typedef __attribute__((ext_vector_type(4))) float f32x4;
typedef __attribute__((ext_vector_type(4))) unsigned int u32x4;

#define NN_TOT 16384   // B*N
#define SLW 72         // slab row stride in shorts (64 cols + 8 pad)

__device__ __forceinline__ uint32_t pk_bf16(float a, float b) {
  uint32_t r;
  asm("v_cvt_pk_bf16_f32 %0, %1, %2" : "=v"(r) : "v"(a), "v"(b));
  return r;  // low = bf16(a), high = bf16(b)
}
__device__ __forceinline__ float lo_f(uint32_t p) {
  return __builtin_bit_cast(float, p << 16);
}
__device__ __forceinline__ float hi_f(uint32_t p) {
  return __builtin_bit_cast(float, p & 0xffff0000u);
}
__device__ __forceinline__ short f2bf_rne(float f) {   // prep only
  uint32_t u = __builtin_bit_cast(uint32_t, f);
  uint32_t r = (u + 0x7FFFu + ((u >> 16) & 1u)) >> 16;
  return (short)r;
}
__device__ __forceinline__ float bf2f(unsigned short s) {
  uint32_t u = ((uint32_t)s) << 16;
  return __builtin_bit_cast(float, u);
}

__global__ __launch_bounds__(256) void prep_frags(
    const float* __restrict__ Wq, const float* __restrict__ Wkv,
    const float* __restrict__ Wp2, const float* __restrict__ Wa1,
    const float* __restrict__ Wa2, const float* __restrict__ Wo,
    short* __restrict__ fqh, short* __restrict__ fql,
    short* __restrict__ fwp2, short* __restrict__ fwa1, short* __restrict__ fwa2,
    short* __restrict__ fwoh, short* __restrict__ fwol) {
  int r = blockIdx.x * 256 + threadIdx.x;   // grid = 44*256 = 11264 exact
  if (r < 3072) {
    int t = r >> 7, rem = r & 127, s = rem >> 6, lane = rem & 63;
    int quad = lane >> 4, l15 = lane & 15;
    int col = t * 16 + l15;
    #pragma unroll
    for (int j = 0; j < 8; j++) {
      int i = 32 * s + quad * 8 + j;
      float wv = (col < 128) ? Wq[i * 128 + col] : Wkv[i * 256 + (col - 128)];
      short hi = f2bf_rne(wv);
      fqh[r * 8 + j] = hi;
      fql[r * 8 + j] = f2bf_rne(wv - bf2f((unsigned short)hi));
    }
  } else {
    int r2 = r - 3072;
    int mat = r2 >> 11;        // 0:Wp2 1:Wa1 2:Wa2 3:Wo
    int rr = r2 & 2047;
    int t = rr >> 8, rem = rr & 255, s = rem >> 6, lane = rem & 63;
    int quad = lane >> 4, l15 = lane & 15;
    int col = t * 16 + l15;
    const float* W = (mat == 0) ? Wp2 : (mat == 1) ? Wa1 : (mat == 2) ? Wa2 : Wo;
    #pragma unroll
    for (int j = 0; j < 8; j++) {
      int i = 32 * s + quad * 8 + j;
      float wv = W[i * 128 + col];
      short hi = f2bf_rne(wv);
      if (mat == 3) {
        fwoh[rr * 8 + j] = hi;
        fwol[rr * 8 + j] = f2bf_rne(wv - bf2f((unsigned short)hi));
      } else if (mat == 0) fwp2[rr * 8 + j] = hi;
      else if (mat == 1)   fwa1[rr * 8 + j] = hi;
      else                 fwa2[rr * 8 + j] = hi;
    }
  }
}

__device__ __forceinline__ void split_frag(const f32x4 x0, const f32x4 x1,
                                           short8& ah, short8& al) {
  uint32_t h01 = pk_bf16(x0[0], x0[1]);
  uint32_t h23 = pk_bf16(x0[2], x0[3]);
  uint32_t h45 = pk_bf16(x1[0], x1[1]);
  uint32_t h67 = pk_bf16(x1[2], x1[3]);
  u32x4 hh = {h01, h23, h45, h67};
  ah = __builtin_bit_cast(short8, hh);
  uint32_t l01 = pk_bf16(x0[0] - lo_f(h01), x0[1] - hi_f(h01));
  uint32_t l23 = pk_bf16(x0[2] - lo_f(h23), x0[3] - hi_f(h23));
  uint32_t l45 = pk_bf16(x1[0] - lo_f(h45), x1[1] - hi_f(h45));
  uint32_t l67 = pk_bf16(x1[2] - lo_f(h67), x1[3] - hi_f(h67));
  u32x4 ll = {l01, l23, l45, l67};
  al = __builtin_bit_cast(short8, ll);
}

// ---------------------------------------------------------------------------
// q,k,v projection. Block = 256 thr (4 waves), one section per block
// (0=q f32, 1=k bf16, 2=v bf16); section B-slice (32 KB hi+lo) in LDS.
// ---------------------------------------------------------------------------
__global__ __launch_bounds__(256) void qkv_kernel(
    const float* __restrict__ x, const float* __restrict__ bq,
    const float* __restrict__ bkv,
    const short* __restrict__ fqh, const short* __restrict__ fql,
    float* __restrict__ q, unsigned short* __restrict__ ko,
    unsigned short* __restrict__ vo) {
  __shared__ __align__(16) short sBq[16384];   // hi [0..8191], lo [8192..16383]
  const int tid = threadIdx.x;
  const int sec = blockIdx.x >> 8;             // 0..2
  const int gq = blockIdx.x & 255;
  const int w = tid >> 6, lane = tid & 63;
  const int quad = lane >> 4, l15 = lane & 15;

  {  // stage 16 KB hi + 16 KB lo of this section's frag rows
    const u32x4* sh = reinterpret_cast<const u32x4*>(fqh + sec * 8192);
    const u32x4* sl = reinterpret_cast<const u32x4*>(fql + sec * 8192);
    u32x4* dh = reinterpret_cast<u32x4*>(sBq);
    u32x4* dl = reinterpret_cast<u32x4*>(sBq + 8192);
    #pragma unroll
    for (int i = 0; i < 4; i++) {
      dh[tid + i * 256] = sh[tid + i * 256];
      dl[tid + i * 256] = sl[tid + i * 256];
    }
  }

  const int base = (gq * 4 + w) * 16;
  short8 ah[2], al[2];
  #pragma unroll
  for (int s = 0; s < 2; s++) {
    const float* xp = x + (base + l15) * 64 + 32 * s + quad * 8;
    split_frag(*reinterpret_cast<const f32x4*>(xp),
               *reinterpret_cast<const f32x4*>(xp + 4), ah[s], al[s]);
  }
  __syncthreads();

  #pragma unroll
  for (int tt = 0; tt < 8; tt++) {
    f32x4 acc = {0.f, 0.f, 0.f, 0.f};
    #pragma unroll
    for (int s = 0; s < 2; s++) {
      int rt = tt * 2 + s;
      short8 bh = *reinterpret_cast<const short8*>(sBq + rt * 512 + lane * 8);
      short8 bl = *reinterpret_cast<const short8*>(sBq + 8192 + rt * 512 + lane * 8);
      acc = __builtin_amdgcn_mfma_f32_16x16x32_bf16(ah[s], bh, acc, 0, 0, 0);
      acc = __builtin_amdgcn_mfma_f32_16x16x32_bf16(ah[s], bl, acc, 0, 0, 0);
      acc = __builtin_amdgcn_mfma_f32_16x16x32_bf16(al[s], bh, acc, 0, 0, 0);
    }
    int cl = tt * 16 + l15;                       // column within section
    if (sec == 0) {
      float bias = bq[cl];
      #pragma unroll
      for (int r = 0; r < 4; r++)
        q[(base + quad * 4 + r) * 128 + cl] = acc[r] + bias;
    } else {
      float bias = bkv[(sec - 1) * 128 + cl];
      unsigned short* dst = (sec == 1) ? ko : vo;
      #pragma unroll
      for (int r = 0; r < 4; r++) {
        float vv = acc[r] + bias;
        dst[(base + quad * 4 + r) * 128 + cl] = (unsigned short)pk_bf16(vv, vv);
      }
    }
  }
}

// ---------------------------------------------------------------------------
// Fused attention + Wo. Block = 512 thr (8 waves), 8 nodes (1/wave), 52 KB
// LDS -> 3 blocks/CU (24 waves). sB (32 KB) cycled Wp2 / Wa1 / Wa2.
// ---------------------------------------------------------------------------
__global__ __launch_bounds__(512, 6) void fused_attn_wo(
    const float* __restrict__ pos, const int* __restrict__ idx,
    const float* __restrict__ Wp1, const float* __restrict__ bp1,
    const float* __restrict__ bp2, const float* __restrict__ ba1,
    const float* __restrict__ ba2,
    const short* __restrict__ fwp2, const short* __restrict__ fwa1,
    const short* __restrict__ fwa2,
    const short* __restrict__ fwoh, const short* __restrict__ fwol,
    const float* __restrict__ bo,
    const float* __restrict__ qg, const unsigned short* __restrict__ kg,
    const unsigned short* __restrict__ vg, float* __restrict__ out) {
  __shared__ __align__(16) short sB[16384];                   // 32 KB, cycled
  __shared__ __align__(16) unsigned short slab[8][16 * SLW];  // 18 KB half-width
  __shared__ float spd[8][16][3];
  __shared__ int sidx[8][16];
  // sagg overlays slab (8 rows x 132 f32 = 4224 B <= 18432 B). All slab
  // round-trip reads finish before barrier 5; sagg writes follow GEMM3.
  float (*sagg)[132] = reinterpret_cast<float(*)[132]>(&slab[0][0]);

  const int tid = threadIdx.x;
  const int w = tid >> 6;
  const int lane = tid & 63;
  const int quad = lane >> 4, l15 = lane & 15;
  const int nb0 = blockIdx.x * 8;
  const int node = nb0 + w;
  unsigned short* myslab = &slab[w][0];

  // ---- neighbor idx + pos_diff (wave-private) ----
  if (lane < 16) {
    int ji = idx[node * 16 + lane];
    int jn = ((node >> 13) << 13) + ji;
    sidx[w][lane] = jn;
    spd[w][lane][0] = pos[node * 3 + 0] - pos[jn * 3 + 0];
    spd[w][lane][1] = pos[node * 3 + 1] - pos[jn * 3 + 1];
    spd[w][lane][2] = pos[node * 3 + 2] - pos[jn * 3 + 2];
  }

  // ---- stage sB <- Wp2 frags (32 KB, all threads) ----
  {
    const u32x4* s4 = reinterpret_cast<const u32x4*>(fwp2);
    u32x4* d4 = reinterpret_cast<u32x4*>(sB);
    #pragma unroll
    for (int i = 0; i < 4; i++) d4[tid + i * 512] = s4[tid + i * 512];
  }

  // ---- pos MLP layer 1 -> slab (two column-phases) -> aP frags ----
  short8 aP[4];
  #pragma unroll
  for (int p = 0; p < 2; p++) {
    const int c = lane + p * 64;           // channel; slab col = lane
    float wp0 = Wp1[c], wp1 = Wp1[128 + c], wp2v = Wp1[256 + c], bb = bp1[c];
    #pragma unroll
    for (int m = 0; m < 16; m++) {
      float h = fmaxf(bb + spd[w][m][0] * wp0 + spd[w][m][1] * wp1 +
                           spd[w][m][2] * wp2v, 0.f);
      myslab[m * SLW + lane] = (unsigned short)pk_bf16(h, h);
    }
    #pragma unroll
    for (int ss = 0; ss < 2; ss++)
      aP[p * 2 + ss] = *reinterpret_cast<const short8*>(
          myslab + l15 * SLW + 32 * ss + quad * 8);
  }
  __syncthreads();   // barrier 1: sB = Wp2 ready

  // ---- k gather (packed bf16; latency hides under GEMM1) ----
  short8 k_pk[4];
  {
    const unsigned short* kp = kg + sidx[w][l15] * 128;
    #pragma unroll
    for (int s = 0; s < 4; s++)
      k_pk[s] = *reinterpret_cast<const short8*>(kp + 32 * s + quad * 8);
  }

  f32x4 acc[8];

  // ---- GEMM1: pos_enc = pos_hidden @ Wp2 ----
  #pragma unroll
  for (int t = 0; t < 8; t++) acc[t] = (f32x4){0.f, 0.f, 0.f, 0.f};
  #pragma unroll
  for (int s = 0; s < 4; s++) {
    #pragma unroll
    for (int t = 0; t < 8; t++) {
      short8 bf = *reinterpret_cast<const short8*>(sB + ((t * 4 + s) * 64 + lane) * 8);
      acc[t] = __builtin_amdgcn_mfma_f32_16x16x32_bf16(aP[s], bf, acc[t], 0, 0, 0);
    }
  }
  __syncthreads();   // barrier 2: all waves done reading Wp2

  // ---- restage sB <- Wa1 (overlaps pe-stage below) ----
  {
    const u32x4* s4 = reinterpret_cast<const u32x4*>(fwa1);
    u32x4* d4 = reinterpret_cast<u32x4*>(sB);
    #pragma unroll
    for (int i = 0; i < 4; i++) d4[tid + i * 512] = s4[tid + i * 512];
  }

  // ---- pe = acc + bp2: keep packed pe; (pe - q) -> slab (2 phases) -> a2 ----
  uint32_t pe_pk[8][2];
  short8 a2[4];
  {
    const float* qrow = qg + node * 128;
    #pragma unroll
    for (int p = 0; p < 2; p++) {
      #pragma unroll
      for (int tt = 0; tt < 4; tt++) {
        int t = p * 4 + tt;
        int c = 16 * t + l15;
        float bb = bp2[c];
        float qv = qrow[c];               // q in C/D layout: one scalar per t
        float f0 = acc[t][0] + bb, f1 = acc[t][1] + bb;
        float f2 = acc[t][2] + bb, f3 = acc[t][3] + bb;
        pe_pk[t][0] = pk_bf16(f0, f1);
        pe_pk[t][1] = pk_bf16(f2, f3);
        uint32_t g01 = pk_bf16(f0 - qv, f1 - qv);
        uint32_t g23 = pk_bf16(f2 - qv, f3 - qv);
        int cl = 16 * tt + l15;           // slab column (0..63)
        myslab[(quad * 4 + 0) * SLW + cl] = (unsigned short)g01;
        myslab[(quad * 4 + 1) * SLW + cl] = (unsigned short)(g01 >> 16);
        myslab[(quad * 4 + 2) * SLW + cl] = (unsigned short)g23;
        myslab[(quad * 4 + 3) * SLW + cl] = (unsigned short)(g23 >> 16);
      }
      #pragma unroll
      for (int ss = 0; ss < 2; ss++) {
        int s = p * 2 + ss;
        short8 pq = *reinterpret_cast<const short8*>(
            myslab + l15 * SLW + 32 * ss + quad * 8);
        short8 kk = k_pk[s];
        u32x4 av = {pk_bf16(bf2f((unsigned short)kk[0]) + bf2f((unsigned short)pq[0]),
                            bf2f((unsigned short)kk[1]) + bf2f((unsigned short)pq[1])),
                    pk_bf16(bf2f((unsigned short)kk[2]) + bf2f((unsigned short)pq[2]),
                            bf2f((unsigned short)kk[3]) + bf2f((unsigned short)pq[3])),
                    pk_bf16(bf2f((unsigned short)kk[4]) + bf2f((unsigned short)pq[4]),
                            bf2f((unsigned short)kk[5]) + bf2f((unsigned short)pq[5])),
                    pk_bf16(bf2f((unsigned short)kk[6]) + bf2f((unsigned short)pq[6]),
                            bf2f((unsigned short)kk[7]) + bf2f((unsigned short)pq[7]))};
        a2[s] = __builtin_bit_cast(short8, av);
      }
    }
  }
  __syncthreads();   // barrier 3: sB = Wa1 ready

  // ---- GEMM2: hidden = relu(rel @ Wa1 + ba1) ----
  #pragma unroll
  for (int t = 0; t < 8; t++) acc[t] = (f32x4){0.f, 0.f, 0.f, 0.f};
  #pragma unroll
  for (int s = 0; s < 4; s++) {
    #pragma unroll
    for (int t = 0; t < 8; t++) {
      short8 bf = *reinterpret_cast<const short8*>(sB + ((t * 4 + s) * 64 + lane) * 8);
      acc[t] = __builtin_amdgcn_mfma_f32_16x16x32_bf16(a2[s], bf, acc[t], 0, 0, 0);
    }
  }
  __syncthreads();   // barrier 4: all waves done reading Wa1

  // ---- restage sB <- Wa2 (overlaps relu-stage below) ----
  {
    const u32x4* s4 = reinterpret_cast<const u32x4*>(fwa2);
    u32x4* d4 = reinterpret_cast<u32x4*>(sB);
    #pragma unroll
    for (int i = 0; i < 4; i++) d4[tid + i * 512] = s4[tid + i * 512];
  }

  // ---- relu + ba1 -> slab (2 phases) -> a3 frags ----
  short8 a3[4];
  #pragma unroll
  for (int p = 0; p < 2; p++) {
    #pragma unroll
    for (int tt = 0; tt < 4; tt++) {
      int t = p * 4 + tt;
      int c = 16 * t + l15;
      float bb = ba1[c];
      uint32_t p01 = pk_bf16(fmaxf(acc[t][0] + bb, 0.f), fmaxf(acc[t][1] + bb, 0.f));
      uint32_t p23 = pk_bf16(fmaxf(acc[t][2] + bb, 0.f), fmaxf(acc[t][3] + bb, 0.f));
      int cl = 16 * tt + l15;
      myslab[(quad * 4 + 0) * SLW + cl] = (unsigned short)p01;
      myslab[(quad * 4 + 1) * SLW + cl] = (unsigned short)(p01 >> 16);
      myslab[(quad * 4 + 2) * SLW + cl] = (unsigned short)p23;
      myslab[(quad * 4 + 3) * SLW + cl] = (unsigned short)(p23 >> 16);
    }
    #pragma unroll
    for (int ss = 0; ss < 2; ss++)
      a3[p * 2 + ss] = *reinterpret_cast<const short8*>(
          myslab + l15 * SLW + 32 * ss + quad * 8);
  }
  __syncthreads();   // barrier 5: sB = Wa2 ready; all slab reads done

  // ---- GEMM3: attn = hidden @ Wa2 + ba2 ----
  #pragma unroll
  for (int t = 0; t < 8; t++) acc[t] = (f32x4){0.f, 0.f, 0.f, 0.f};
  #pragma unroll
  for (int s = 0; s < 4; s++) {
    #pragma unroll
    for (int t = 0; t < 8; t++) {
      short8 bf = *reinterpret_cast<const short8*>(sB + ((t * 4 + s) * 64 + lane) * 8);
      acc[t] = __builtin_amdgcn_mfma_f32_16x16x32_bf16(a3[s], bf, acc[t], 0, 0, 0);
    }
  }

  // ---- softmax over K=16 + aggregation (v bf16 gathers, pe from regs) ----
  int vb[4];
  #pragma unroll
  for (int r = 0; r < 4; r++) vb[r] = sidx[w][quad * 4 + r] * 128;

  #pragma unroll
  for (int t = 0; t < 8; t++) {
    int c = 16 * t + l15;
    float bb = ba2[c];
    float g0 = acc[t][0] + bb, g1 = acc[t][1] + bb;
    float g2 = acc[t][2] + bb, g3 = acc[t][3] + bb;
    float mx = fmaxf(fmaxf(g0, g1), fmaxf(g2, g3));
    mx = fmaxf(mx, __shfl_xor(mx, 16));
    mx = fmaxf(mx, __shfl_xor(mx, 32));
    float e0 = __expf(g0 - mx), e1 = __expf(g1 - mx);
    float e2 = __expf(g2 - mx), e3 = __expf(g3 - mx);
    float ls = e0 + e1 + e2 + e3;
    ls += __shfl_xor(ls, 16);
    ls += __shfl_xor(ls, 32);
    float pe0 = lo_f(pe_pk[t][0]), pe1 = hi_f(pe_pk[t][0]);
    float pe2 = lo_f(pe_pk[t][1]), pe3 = hi_f(pe_pk[t][1]);
    float p = e0 * (bf2f(vg[vb[0] + c]) + pe0)
            + e1 * (bf2f(vg[vb[1] + c]) + pe1)
            + e2 * (bf2f(vg[vb[2] + c]) + pe2)
            + e3 * (bf2f(vg[vb[3] + c]) + pe3);
    p += __shfl_xor(p, 16);
    p += __shfl_xor(p, 32);
    if (quad == 0) sagg[w][c] = p * __builtin_amdgcn_rcpf(ls);
  }
  __syncthreads();   // barrier 6: sagg rows 0-7 complete

  // ---- fused Wo: out = sagg @ Wo + bo (wave w = output tile w) ----
  {
    short8 ah[4], al[4];
    #pragma unroll
    for (int s = 0; s < 4; s++) {
      f32x4 x0 = *reinterpret_cast<const f32x4*>(&sagg[l15][32 * s + quad * 8]);
      f32x4 x1 = *reinterpret_cast<const f32x4*>(&sagg[l15][32 * s + quad * 8 + 4]);
      split_frag(x0, x1, ah[s], al[s]);
    }
    f32x4 aw = {0.f, 0.f, 0.f, 0.f};
    #pragma unroll
    for (int s = 0; s < 4; s++) {
      short8 bh = *reinterpret_cast<const short8*>(fwoh + ((w * 4 + s) * 64 + lane) * 8);
      short8 bl = *reinterpret_cast<const short8*>(fwol + ((w * 4 + s) * 64 + lane) * 8);
      aw = __builtin_amdgcn_mfma_f32_16x16x32_bf16(ah[s], bh, aw, 0, 0, 0);
      aw = __builtin_amdgcn_mfma_f32_16x16x32_bf16(ah[s], bl, aw, 0, 0, 0);
      aw = __builtin_amdgcn_mfma_f32_16x16x32_bf16(al[s], bh, aw, 0, 0, 0);
    }
    int c = 16 * w + l15;
    float bb = bo[c];
    if (quad < 2) {   // rows 0-7 valid (8 nodes/block)
      #pragma unroll
      for (int r = 0; r < 4; r++)
        out[(nb0 + quad * 4 + r) * 128 + c] = aw[r] + bb;
    }
  }
}

extern "C" void kernel_launch(void* const* d_in, const int* in_sizes, int n_in,
                              void* d_out, int out_size, void* d_ws, size_t ws_size,
                              hipStream_t stream) {
  const float* x   = (const float*)d_in[0];
  const float* pos = (const float*)d_in[1];
  const int*   idx = (const int*)d_in[2];
  const float* Wq  = (const float*)d_in[3];
  const float* bq  = (const float*)d_in[4];
  const float* Wkv = (const float*)d_in[5];
  const float* bkv = (const float*)d_in[6];
  const float* Wp1 = (const float*)d_in[7];
  const float* bp1 = (const float*)d_in[8];
  const float* Wp2 = (const float*)d_in[9];
  const float* bp2 = (const float*)d_in[10];
  const float* Wa1 = (const float*)d_in[11];
  const float* ba1 = (const float*)d_in[12];
  const float* Wa2 = (const float*)d_in[13];
  const float* ba2 = (const float*)d_in[14];
  const float* Wo  = (const float*)d_in[15];
  const float* bo  = (const float*)d_in[16];

  char* ws = (char*)d_ws;
  short* fqh  = (short*)(ws + 0);
  short* fql  = (short*)(ws + 49152);
  short* fwp2 = (short*)(ws + 98304);
  short* fwa1 = (short*)(ws + 131072);
  short* fwa2 = (short*)(ws + 163840);
  short* fwoh = (short*)(ws + 196608);
  short* fwol = (short*)(ws + 229376);
  float* qb = (float*)(ws + 262144);                               // 8 MB f32
  unsigned short* kb = (unsigned short*)(ws + 262144 + 8388608);   // 4 MB bf16
  unsigned short* vb = kb + NN_TOT * 128;                          // 4 MB bf16

  prep_frags<<<44, 256, 0, stream>>>(Wq, Wkv, Wp2, Wa1, Wa2, Wo,
                                     fqh, fql, fwp2, fwa1, fwa2, fwoh, fwol);
  qkv_kernel<<<768, 256, 0, stream>>>(x, bq, bkv, fqh, fql, qb, kb, vb);
  fused_attn_wo<<<2048, 512, 0, stream>>>(pos, idx, Wp1, bp1, bp2, ba1, ba2,
                                          fwp2, fwa1, fwa2, fwoh, fwol, bo,
                                          qb, kb, vb, (float*)d_out);
}

// Round 9
// 168.234 us; speedup vs baseline: 1.3904x; 1.0395x over previous
//
#include <hip/hip_runtime.h>
#include <stdint.h>

// ---------------------------------------------------------------------------
// MultiHeadPointAttention (B=2, N=8192, K=16, H=4, Cin=64, Cout=128, D=32)
//
//   prep_frags    : weights -> bf16 MFMA B-fragment layout in ws
//   qkv_kernel    : q(f32),k,v(bf16) = x @ [Wq|Wkv] + bias; per-block LDS B-slice
//   fused_attn_wo : block=512 (8 waves), NPW=1, 52 KB LDS -> 3 blocks/CU.
//                   32 KB sB cycled Wp2->Wa1->Wa2, 6 barriers. GEMMs run as
//                   t-PAIR loops with FUSED epilogues (pe / relu / softmax are
//                   all per-t independent; softmax over K=16 lives entirely
//                   inside tile t) -> acc live = 8 regs not 32. ba2 dropped
//                   (constant over K per channel -> cancels in softmax).
//
// R8 lesson: acc[8]=32 regs made total need ~84; (512,6) cap 85 left no
// scheduling slack -> spill (WRITE_SIZE 8->48 MB, the tell). Fused epilogues
// cut the floor by 24 regs.
//
// MFMA 16x16x32 bf16 layouts (HW-verified):
//   A[m][k]: m = lane&15, k = (lane>>4)*8 + j
//   B[k][n]: n = lane&15, k = (lane>>4)*8 + j
//   D[r][c]: c = lane&15, r = (lane>>4)*4 + reg
// ---------------------------------------------------------------------------

typedef __attribute__((ext_vector_type(8))) short short8;
typedef __attribute__((ext_vector_type(4))) float f32x4;
typedef __attribute__((ext_vector_type(4))) unsigned int u32x4;

#define NN_TOT 16384   // B*N
#define SLW 72         // slab row stride in shorts (64 cols + 8 pad)

__device__ __forceinline__ uint32_t pk_bf16(float a, float b) {
  uint32_t r;
  asm("v_cvt_pk_bf16_f32 %0, %1, %2" : "=v"(r) : "v"(a), "v"(b));
  return r;  // low = bf16(a), high = bf16(b)
}
__device__ __forceinline__ float lo_f(uint32_t p) {
  return __builtin_bit_cast(float, p << 16);
}
__device__ __forceinline__ float hi_f(uint32_t p) {
  return __builtin_bit_cast(float, p & 0xffff0000u);
}
__device__ __forceinline__ short f2bf_rne(float f) {   // prep only
  uint32_t u = __builtin_bit_cast(uint32_t, f);
  uint32_t r = (u + 0x7FFFu + ((u >> 16) & 1u)) >> 16;
  return (short)r;
}
__device__ __forceinline__ float bf2f(unsigned short s) {
  uint32_t u = ((uint32_t)s) << 16;
  return __builtin_bit_cast(float, u);
}

__global__ __launch_bounds__(256) void prep_frags(
    const float* __restrict__ Wq, const float* __restrict__ Wkv,
    const float* __restrict__ Wp2, const float* __restrict__ Wa1,
    const float* __restrict__ Wa2, const float* __restrict__ Wo,
    short* __restrict__ fqh, short* __restrict__ fql,
    short* __restrict__ fwp2, short* __restrict__ fwa1, short* __restrict__ fwa2,
    short* __restrict__ fwoh, short* __restrict__ fwol) {
  int r = blockIdx.x * 256 + threadIdx.x;   // grid = 44*256 = 11264 exact
  if (r < 3072) {
    int t = r >> 7, rem = r & 127, s = rem >> 6, lane = rem & 63;
    int quad = lane >> 4, l15 = lane & 15;
    int col = t * 16 + l15;
    #pragma unroll
    for (int j = 0; j < 8; j++) {
      int i = 32 * s + quad * 8 + j;
      float wv = (col < 128) ? Wq[i * 128 + col] : Wkv[i * 256 + (col - 128)];
      short hi = f2bf_rne(wv);
      fqh[r * 8 + j] = hi;
      fql[r * 8 + j] = f2bf_rne(wv - bf2f((unsigned short)hi));
    }
  } else {
    int r2 = r - 3072;
    int mat = r2 >> 11;        // 0:Wp2 1:Wa1 2:Wa2 3:Wo
    int rr = r2 & 2047;
    int t = rr >> 8, rem = rr & 255, s = rem >> 6, lane = rem & 63;
    int quad = lane >> 4, l15 = lane & 15;
    int col = t * 16 + l15;
    const float* W = (mat == 0) ? Wp2 : (mat == 1) ? Wa1 : (mat == 2) ? Wa2 : Wo;
    #pragma unroll
    for (int j = 0; j < 8; j++) {
      int i = 32 * s + quad * 8 + j;
      float wv = W[i * 128 + col];
      short hi = f2bf_rne(wv);
      if (mat == 3) {
        fwoh[rr * 8 + j] = hi;
        fwol[rr * 8 + j] = f2bf_rne(wv - bf2f((unsigned short)hi));
      } else if (mat == 0) fwp2[rr * 8 + j] = hi;
      else if (mat == 1)   fwa1[rr * 8 + j] = hi;
      else                 fwa2[rr * 8 + j] = hi;
    }
  }
}

__device__ __forceinline__ void split_frag(const f32x4 x0, const f32x4 x1,
                                           short8& ah, short8& al) {
  uint32_t h01 = pk_bf16(x0[0], x0[1]);
  uint32_t h23 = pk_bf16(x0[2], x0[3]);
  uint32_t h45 = pk_bf16(x1[0], x1[1]);
  uint32_t h67 = pk_bf16(x1[2], x1[3]);
  u32x4 hh = {h01, h23, h45, h67};
  ah = __builtin_bit_cast(short8, hh);
  uint32_t l01 = pk_bf16(x0[0] - lo_f(h01), x0[1] - hi_f(h01));
  uint32_t l23 = pk_bf16(x0[2] - lo_f(h23), x0[3] - hi_f(h23));
  uint32_t l45 = pk_bf16(x1[0] - lo_f(h45), x1[1] - hi_f(h45));
  uint32_t l67 = pk_bf16(x1[2] - lo_f(h67), x1[3] - hi_f(h67));
  u32x4 ll = {l01, l23, l45, l67};
  al = __builtin_bit_cast(short8, ll);
}

// ---------------------------------------------------------------------------
// q,k,v projection. Block = 256 thr (4 waves), one section per block
// (0=q f32, 1=k bf16, 2=v bf16); section B-slice (32 KB hi+lo) in LDS.
// ---------------------------------------------------------------------------
__global__ __launch_bounds__(256) void qkv_kernel(
    const float* __restrict__ x, const float* __restrict__ bq,
    const float* __restrict__ bkv,
    const short* __restrict__ fqh, const short* __restrict__ fql,
    float* __restrict__ q, unsigned short* __restrict__ ko,
    unsigned short* __restrict__ vo) {
  __shared__ __align__(16) short sBq[16384];   // hi [0..8191], lo [8192..16383]
  const int tid = threadIdx.x;
  const int sec = blockIdx.x >> 8;             // 0..2
  const int gq = blockIdx.x & 255;
  const int w = tid >> 6, lane = tid & 63;
  const int quad = lane >> 4, l15 = lane & 15;

  {  // stage 16 KB hi + 16 KB lo of this section's frag rows
    const u32x4* sh = reinterpret_cast<const u32x4*>(fqh + sec * 8192);
    const u32x4* sl = reinterpret_cast<const u32x4*>(fql + sec * 8192);
    u32x4* dh = reinterpret_cast<u32x4*>(sBq);
    u32x4* dl = reinterpret_cast<u32x4*>(sBq + 8192);
    #pragma unroll
    for (int i = 0; i < 4; i++) {
      dh[tid + i * 256] = sh[tid + i * 256];
      dl[tid + i * 256] = sl[tid + i * 256];
    }
  }

  const int base = (gq * 4 + w) * 16;
  short8 ah[2], al[2];
  #pragma unroll
  for (int s = 0; s < 2; s++) {
    const float* xp = x + (base + l15) * 64 + 32 * s + quad * 8;
    split_frag(*reinterpret_cast<const f32x4*>(xp),
               *reinterpret_cast<const f32x4*>(xp + 4), ah[s], al[s]);
  }
  __syncthreads();

  #pragma unroll
  for (int tt = 0; tt < 8; tt++) {
    f32x4 acc = {0.f, 0.f, 0.f, 0.f};
    #pragma unroll
    for (int s = 0; s < 2; s++) {
      int rt = tt * 2 + s;
      short8 bh = *reinterpret_cast<const short8*>(sBq + rt * 512 + lane * 8);
      short8 bl = *reinterpret_cast<const short8*>(sBq + 8192 + rt * 512 + lane * 8);
      acc = __builtin_amdgcn_mfma_f32_16x16x32_bf16(ah[s], bh, acc, 0, 0, 0);
      acc = __builtin_amdgcn_mfma_f32_16x16x32_bf16(ah[s], bl, acc, 0, 0, 0);
      acc = __builtin_amdgcn_mfma_f32_16x16x32_bf16(al[s], bh, acc, 0, 0, 0);
    }
    int cl = tt * 16 + l15;                       // column within section
    if (sec == 0) {
      float bias = bq[cl];
      #pragma unroll
      for (int r = 0; r < 4; r++)
        q[(base + quad * 4 + r) * 128 + cl] = acc[r] + bias;
    } else {
      float bias = bkv[(sec - 1) * 128 + cl];
      unsigned short* dst = (sec == 1) ? ko : vo;
      #pragma unroll
      for (int r = 0; r < 4; r++) {
        float vv = acc[r] + bias;
        dst[(base + quad * 4 + r) * 128 + cl] = (unsigned short)pk_bf16(vv, vv);
      }
    }
  }
}

// ---------------------------------------------------------------------------
// Fused attention + Wo. Block = 512 thr (8 waves), 8 nodes (1/wave), 52 KB
// LDS -> 3 blocks/CU. sB (32 KB) cycled Wp2 / Wa1 / Wa2. t-pair fused
// epilogues keep acc live at 8 regs.
// ---------------------------------------------------------------------------
__global__ __launch_bounds__(512, 6) void fused_attn_wo(
    const float* __restrict__ pos, const int* __restrict__ idx,
    const float* __restrict__ Wp1, const float* __restrict__ bp1,
    const float* __restrict__ bp2, const float* __restrict__ ba1,
    const short* __restrict__ fwp2, const short* __restrict__ fwa1,
    const short* __restrict__ fwa2,
    const short* __restrict__ fwoh, const short* __restrict__ fwol,
    const float* __restrict__ bo,
    const float* __restrict__ qg, const unsigned short* __restrict__ kg,
    const unsigned short* __restrict__ vg, float* __restrict__ out) {
  __shared__ __align__(16) short sB[16384];                   // 32 KB, cycled
  __shared__ __align__(16) unsigned short slab[8][16 * SLW];  // 18 KB half-width
  __shared__ float spd[8][16][3];
  __shared__ int sidx[8][16];
  // sagg overlays slab (8 rows x 132 f32 = 4224 B). All slab reads complete
  // before barrier 5; sagg writes follow (every wave passes barrier 5 first).
  float (*sagg)[132] = reinterpret_cast<float(*)[132]>(&slab[0][0]);

  const int tid = threadIdx.x;
  const int w = tid >> 6;
  const int lane = tid & 63;
  const int quad = lane >> 4, l15 = lane & 15;
  const int nb0 = blockIdx.x * 8;
  const int node = nb0 + w;
  unsigned short* myslab = &slab[w][0];

  // ---- neighbor idx + pos_diff (wave-private) ----
  if (lane < 16) {
    int ji = idx[node * 16 + lane];
    int jn = ((node >> 13) << 13) + ji;
    sidx[w][lane] = jn;
    spd[w][lane][0] = pos[node * 3 + 0] - pos[jn * 3 + 0];
    spd[w][lane][1] = pos[node * 3 + 1] - pos[jn * 3 + 1];
    spd[w][lane][2] = pos[node * 3 + 2] - pos[jn * 3 + 2];
  }

  // ---- stage sB <- Wp2 frags (32 KB, all threads) ----
  {
    const u32x4* s4 = reinterpret_cast<const u32x4*>(fwp2);
    u32x4* d4 = reinterpret_cast<u32x4*>(sB);
    #pragma unroll
    for (int i = 0; i < 4; i++) d4[tid + i * 512] = s4[tid + i * 512];
  }

  // ---- pos MLP layer 1 -> slab (two column-phases) -> aP frags ----
  short8 aP[4];
  #pragma unroll
  for (int p = 0; p < 2; p++) {
    const int c = lane + p * 64;           // channel; slab col = lane
    float wp0 = Wp1[c], wp1 = Wp1[128 + c], wp2v = Wp1[256 + c], bb = bp1[c];
    #pragma unroll
    for (int m = 0; m < 16; m++) {
      float h = fmaxf(bb + spd[w][m][0] * wp0 + spd[w][m][1] * wp1 +
                           spd[w][m][2] * wp2v, 0.f);
      myslab[m * SLW + lane] = (unsigned short)pk_bf16(h, h);
    }
    #pragma unroll
    for (int ss = 0; ss < 2; ss++)
      aP[p * 2 + ss] = *reinterpret_cast<const short8*>(
          myslab + l15 * SLW + 32 * ss + quad * 8);
  }
  __syncthreads();   // barrier 1: sB = Wp2 ready

  // ---- gathers: k (packed bf16) + q in C/D layout (hide under GEMM1) ----
  short8 k_pk[4];
  float qv[8];
  {
    const unsigned short* kp = kg + sidx[w][l15] * 128;
    #pragma unroll
    for (int s = 0; s < 4; s++)
      k_pk[s] = *reinterpret_cast<const short8*>(kp + 32 * s + quad * 8);
    const float* qrow = qg + node * 128;
    #pragma unroll
    for (int t = 0; t < 8; t++) qv[t] = qrow[16 * t + l15];
  }

  uint32_t pe_pk[8][2];
  short8 a2[4];

  // ---- GEMM1 (t-pairs, fused pe epilogue): pos_enc = pos_hidden @ Wp2 ----
  #pragma unroll
  for (int p = 0; p < 2; p++) {
    #pragma unroll
    for (int half = 0; half < 2; half++) {
      const int t0 = p * 4 + half * 2, t1 = t0 + 1;
      f32x4 aa = {0.f, 0.f, 0.f, 0.f}, ab = {0.f, 0.f, 0.f, 0.f};
      #pragma unroll
      for (int s = 0; s < 4; s++) {
        short8 b0 = *reinterpret_cast<const short8*>(sB + ((t0 * 4 + s) * 64 + lane) * 8);
        short8 b1 = *reinterpret_cast<const short8*>(sB + ((t1 * 4 + s) * 64 + lane) * 8);
        aa = __builtin_amdgcn_mfma_f32_16x16x32_bf16(aP[s], b0, aa, 0, 0, 0);
        ab = __builtin_amdgcn_mfma_f32_16x16x32_bf16(aP[s], b1, ab, 0, 0, 0);
      }
      #pragma unroll
      for (int e = 0; e < 2; e++) {
        const int t = e ? t1 : t0;
        const f32x4 ac = e ? ab : aa;
        float bb = bp2[16 * t + l15];
        float f0 = ac[0] + bb, f1 = ac[1] + bb, f2 = ac[2] + bb, f3 = ac[3] + bb;
        pe_pk[t][0] = pk_bf16(f0, f1);
        pe_pk[t][1] = pk_bf16(f2, f3);
        float q_ = qv[t];
        uint32_t g01 = pk_bf16(f0 - q_, f1 - q_);
        uint32_t g23 = pk_bf16(f2 - q_, f3 - q_);
        int cl = 16 * (t & 3) + l15;
        myslab[(quad * 4 + 0) * SLW + cl] = (unsigned short)g01;
        myslab[(quad * 4 + 1) * SLW + cl] = (unsigned short)(g01 >> 16);
        myslab[(quad * 4 + 2) * SLW + cl] = (unsigned short)g23;
        myslab[(quad * 4 + 3) * SLW + cl] = (unsigned short)(g23 >> 16);
      }
    }
    // build a2 for this phase: rel = k + (pe - q)
    #pragma unroll
    for (int ss = 0; ss < 2; ss++) {
      int s = p * 2 + ss;
      short8 pq = *reinterpret_cast<const short8*>(
          myslab + l15 * SLW + 32 * ss + quad * 8);
      short8 kk = k_pk[s];
      u32x4 av = {pk_bf16(bf2f((unsigned short)kk[0]) + bf2f((unsigned short)pq[0]),
                          bf2f((unsigned short)kk[1]) + bf2f((unsigned short)pq[1])),
                  pk_bf16(bf2f((unsigned short)kk[2]) + bf2f((unsigned short)pq[2]),
                          bf2f((unsigned short)kk[3]) + bf2f((unsigned short)pq[3])),
                  pk_bf16(bf2f((unsigned short)kk[4]) + bf2f((unsigned short)pq[4]),
                          bf2f((unsigned short)kk[5]) + bf2f((unsigned short)pq[5])),
                  pk_bf16(bf2f((unsigned short)kk[6]) + bf2f((unsigned short)pq[6]),
                          bf2f((unsigned short)kk[7]) + bf2f((unsigned short)pq[7]))};
      a2[s] = __builtin_bit_cast(short8, av);
    }
  }
  __syncthreads();   // barrier 2: all waves done reading Wp2

  // ---- restage sB <- Wa1 ----
  {
    const u32x4* s4 = reinterpret_cast<const u32x4*>(fwa1);
    u32x4* d4 = reinterpret_cast<u32x4*>(sB);
    #pragma unroll
    for (int i = 0; i < 4; i++) d4[tid + i * 512] = s4[tid + i * 512];
  }
  __syncthreads();   // barrier 3: sB = Wa1 ready

  // ---- GEMM2 (t-pairs, fused relu epilogue): hidden = relu(rel@Wa1+ba1) ----
  short8 a3[4];
  #pragma unroll
  for (int p = 0; p < 2; p++) {
    #pragma unroll
    for (int half = 0; half < 2; half++) {
      const int t0 = p * 4 + half * 2, t1 = t0 + 1;
      f32x4 aa = {0.f, 0.f, 0.f, 0.f}, ab = {0.f, 0.f, 0.f, 0.f};
      #pragma unroll
      for (int s = 0; s < 4; s++) {
        short8 b0 = *reinterpret_cast<const short8*>(sB + ((t0 * 4 + s) * 64 + lane) * 8);
        short8 b1 = *reinterpret_cast<const short8*>(sB + ((t1 * 4 + s) * 64 + lane) * 8);
        aa = __builtin_amdgcn_mfma_f32_16x16x32_bf16(a2[s], b0, aa, 0, 0, 0);
        ab = __builtin_amdgcn_mfma_f32_16x16x32_bf16(a2[s], b1, ab, 0, 0, 0);
      }
      #pragma unroll
      for (int e = 0; e < 2; e++) {
        const int t = e ? t1 : t0;
        const f32x4 ac = e ? ab : aa;
        float bb = ba1[16 * t + l15];
        uint32_t p01 = pk_bf16(fmaxf(ac[0] + bb, 0.f), fmaxf(ac[1] + bb, 0.f));
        uint32_t p23 = pk_bf16(fmaxf(ac[2] + bb, 0.f), fmaxf(ac[3] + bb, 0.f));
        int cl = 16 * (t & 3) + l15;
        myslab[(quad * 4 + 0) * SLW + cl] = (unsigned short)p01;
        myslab[(quad * 4 + 1) * SLW + cl] = (unsigned short)(p01 >> 16);
        myslab[(quad * 4 + 2) * SLW + cl] = (unsigned short)p23;
        myslab[(quad * 4 + 3) * SLW + cl] = (unsigned short)(p23 >> 16);
      }
    }
    #pragma unroll
    for (int ss = 0; ss < 2; ss++)
      a3[p * 2 + ss] = *reinterpret_cast<const short8*>(
          myslab + l15 * SLW + 32 * ss + quad * 8);
  }
  __syncthreads();   // barrier 4: all waves done reading Wa1

  // ---- restage sB <- Wa2 ----
  {
    const u32x4* s4 = reinterpret_cast<const u32x4*>(fwa2);
    u32x4* d4 = reinterpret_cast<u32x4*>(sB);
    #pragma unroll
    for (int i = 0; i < 4; i++) d4[tid + i * 512] = s4[tid + i * 512];
  }
  __syncthreads();   // barrier 5: sB = Wa2 ready; all slab reads done

  // ---- GEMM3 (t-pairs, fused softmax+agg epilogue). ba2 cancels. ----
  int vb[4];
  #pragma unroll
  for (int r = 0; r < 4; r++) vb[r] = sidx[w][quad * 4 + r] * 128;

  #pragma unroll
  for (int tp = 0; tp < 4; tp++) {
    const int t0 = tp * 2, t1 = t0 + 1;
    f32x4 aa = {0.f, 0.f, 0.f, 0.f}, ab = {0.f, 0.f, 0.f, 0.f};
    #pragma unroll
    for (int s = 0; s < 4; s++) {
      short8 b0 = *reinterpret_cast<const short8*>(sB + ((t0 * 4 + s) * 64 + lane) * 8);
      short8 b1 = *reinterpret_cast<const short8*>(sB + ((t1 * 4 + s) * 64 + lane) * 8);
      aa = __builtin_amdgcn_mfma_f32_16x16x32_bf16(a3[s], b0, aa, 0, 0, 0);
      ab = __builtin_amdgcn_mfma_f32_16x16x32_bf16(a3[s], b1, ab, 0, 0, 0);
    }
    #pragma unroll
    for (int e = 0; e < 2; e++) {
      const int t = e ? t1 : t0;
      const f32x4 ac = e ? ab : aa;
      int c = 16 * t + l15;
      float g0 = ac[0], g1 = ac[1], g2 = ac[2], g3 = ac[3];
      float mx = fmaxf(fmaxf(g0, g1), fmaxf(g2, g3));
      mx = fmaxf(mx, __shfl_xor(mx, 16));
      mx = fmaxf(mx, __shfl_xor(mx, 32));
      float e0 = __expf(g0 - mx), e1 = __expf(g1 - mx);
      float e2 = __expf(g2 - mx), e3 = __expf(g3 - mx);
      float ls = e0 + e1 + e2 + e3;
      ls += __shfl_xor(ls, 16);
      ls += __shfl_xor(ls, 32);
      float pe0 = lo_f(pe_pk[t][0]), pe1 = hi_f(pe_pk[t][0]);
      float pe2 = lo_f(pe_pk[t][1]), pe3 = hi_f(pe_pk[t][1]);
      float pp = e0 * (bf2f(vg[vb[0] + c]) + pe0)
               + e1 * (bf2f(vg[vb[1] + c]) + pe1)
               + e2 * (bf2f(vg[vb[2] + c]) + pe2)
               + e3 * (bf2f(vg[vb[3] + c]) + pe3);
      pp += __shfl_xor(pp, 16);
      pp += __shfl_xor(pp, 32);
      if (quad == 0) sagg[w][c] = pp * __builtin_amdgcn_rcpf(ls);
    }
  }
  __syncthreads();   // barrier 6: sagg rows 0-7 complete

  // ---- fused Wo: out = sagg @ Wo + bo (wave w = output tile w) ----
  {
    short8 ah[4], al[4];
    #pragma unroll
    for (int s = 0; s < 4; s++) {
      f32x4 x0 = *reinterpret_cast<const f32x4*>(&sagg[l15][32 * s + quad * 8]);
      f32x4 x1 = *reinterpret_cast<const f32x4*>(&sagg[l15][32 * s + quad * 8 + 4]);
      split_frag(x0, x1, ah[s], al[s]);
    }
    f32x4 aw = {0.f, 0.f, 0.f, 0.f};
    #pragma unroll
    for (int s = 0; s < 4; s++) {
      short8 bh = *reinterpret_cast<const short8*>(fwoh + ((w * 4 + s) * 64 + lane) * 8);
      short8 bl = *reinterpret_cast<const short8*>(fwol + ((w * 4 + s) * 64 + lane) * 8);
      aw = __builtin_amdgcn_mfma_f32_16x16x32_bf16(ah[s], bh, aw, 0, 0, 0);
      aw = __builtin_amdgcn_mfma_f32_16x16x32_bf16(ah[s], bl, aw, 0, 0, 0);
      aw = __builtin_amdgcn_mfma_f32_16x16x32_bf16(al[s], bh, aw, 0, 0, 0);
    }
    int c = 16 * w + l15;
    float bb = bo[c];
    if (quad < 2) {   // rows 0-7 valid (8 nodes/block)
      #pragma unroll
      for (int r = 0; r < 4; r++)
        out[(nb0 + quad * 4 + r) * 128 + c] = aw[r] + bb;
    }
  }
}

extern "C" void kernel_launch(void* const* d_in, const int* in_sizes, int n_in,
                              void* d_out, int out_size, void* d_ws, size_t ws_size,
                              hipStream_t stream) {
  const float* x   = (const float*)d_in[0];
  const float* pos = (const float*)d_in[1];
  const int*   idx = (const int*)d_in[2];
  const float* Wq  = (const float*)d_in[3];
  const float* bq  = (const float*)d_in[4];
  const float* Wkv = (const float*)d_in[5];
  const float* bkv = (const float*)d_in[6];
  const float* Wp1 = (const float*)d_in[7];
  const float* bp1 = (const float*)d_in[8];
  const float* Wp2 = (const float*)d_in[9];
  const float* bp2 = (const float*)d_in[10];
  const float* Wa1 = (const float*)d_in[11];
  const float* ba1 = (const float*)d_in[12];
  const float* Wa2 = (const float*)d_in[13];
  const float* Wo  = (const float*)d_in[15];
  const float* bo  = (const float*)d_in[16];

  char* ws = (char*)d_ws;
  short* fqh  = (short*)(ws + 0);
  short* fql  = (short*)(ws + 49152);
  short* fwp2 = (short*)(ws + 98304);
  short* fwa1 = (short*)(ws + 131072);
  short* fwa2 = (short*)(ws + 163840);
  short* fwoh = (short*)(ws + 196608);
  short* fwol = (short*)(ws + 229376);
  float* qb = (float*)(ws + 262144);                               // 8 MB f32
  unsigned short* kb = (unsigned short*)(ws + 262144 + 8388608);   // 4 MB bf16
  unsigned short* vb = kb + NN_TOT * 128;                          // 4 MB bf16

  prep_frags<<<44, 256, 0, stream>>>(Wq, Wkv, Wp2, Wa1, Wa2, Wo,
                                     fqh, fql, fwp2, fwa1, fwa2, fwoh, fwol);
  qkv_kernel<<<768, 256, 0, stream>>>(x, bq, bkv, fqh, fql, qb, kb, vb);
  fused_attn_wo<<<2048, 512, 0, stream>>>(pos, idx, Wp1, bp1, bp2, ba1,
                                          fwp2, fwa1, fwa2, fwoh, fwol, bo,
                                          qb, kb, vb, (float*)d_out);
}